// Round 3
// baseline (1204.856 us; speedup 1.0000x reference)
//
#include <hip/hip_runtime.h>
#include <math.h>

#define B_ 16
#define N_ 4096
#define D_ 64
#define H_ 128
#define K_ 32
#define NS_ 1024
#define R2_ 0.04f
#define CAP_ 1024

typedef short short8 __attribute__((ext_vector_type(8)));
typedef float f32x4 __attribute__((ext_vector_type(4)));
typedef unsigned short ushort_t;

static __device__ __forceinline__ short f2bf(float f) {
    unsigned u = __float_as_uint(f);
    unsigned r = (u + 0x7FFFu + ((u >> 16) & 1u)) >> 16;   // round-to-nearest-even
    return (short)r;
}

template<int CTRL, int RM>
static __device__ __forceinline__ unsigned dppmov(unsigned v) {
    // old = v -> masked/invalid lanes keep v (identity for max/min)
    return (unsigned)__builtin_amdgcn_update_dpp((int)v, (int)v, CTRL, RM, 0xF, false);
}

#define DPP_FMAX_STEP(CTRL, RM)                                           \
    {                                                                     \
        float n = __uint_as_float(dppmov<CTRL, RM>(__float_as_uint(wm))); \
        wm = fmaxf(wm, n);                                                \
    }

#define DPP_UMAX_STEP(CTRL, RM)                                           \
    {                                                                     \
        unsigned n = dppmov<CTRL, RM>(cand);                              \
        cand = n > cand ? n : cand;                                       \
    }

#define DPP_UMIN_STEP(CTRL, RM)                                           \
    {                                                                     \
        unsigned n = dppmov<CTRL, RM>(cand);                              \
        cand = n < cand ? n : cand;                                       \
    }

#define DPP_UMIN_STEP_V(var, CTRL, RM)                                    \
    {                                                                     \
        unsigned n = dppmov<CTRL, RM>(var);                               \
        var = n < var ? n : var;                                          \
    }

// ---------------- x -> bf16 pre-convert (RNE, identical to f2bf) ----------
__global__ __launch_bounds__(256) void cvt_kernel(
    const float* __restrict__ x, ushort_t* __restrict__ xb)
{
    const size_t i = ((size_t)blockIdx.x * 256 + threadIdx.x) * 8;
    float4 a = *(const float4*)(x + i);
    float4 c = *(const float4*)(x + i + 4);
    short8 o;
    o[0] = f2bf(a.x); o[1] = f2bf(a.y); o[2] = f2bf(a.z); o[3] = f2bf(a.w);
    o[4] = f2bf(c.x); o[5] = f2bf(c.y); o[6] = f2bf(c.z); o[7] = f2bf(c.w);
    *(short8*)(xb + i) = o;
}

// ---------------- FPS v11: atomicMax tail, branchless wave reduce ----------
// v8 (647us) fit: tail ISSUE ~500cy + exposed latency ~500cy at 1 wave/SIMD.
// v11 cuts both:
//  * branchless wave reduce: fmax-DPP x6 -> readlane -> eq-select ->
//    u32max-DPP x6 (v_max_u32, cheap). No ballot/popc/ffs/divergent tie path.
//    Exact: max d2, then min idx (cand = 4096-pidx, umax). Winner LANE is
//    widx&63 by construction (point p lives in lane p&63).
//  * coords tracked in regs during argmax (+3 cndmask/pt); the winner lane
//    writes them to scoord directly. No lpos4 read, lpos4 deleted.
//  * cross-wave reduce = ONE ds atomicMax(u64) per wave leader; post-barrier
//    read cell + all 4 scoord slots IN PARALLEL, 2-level cndmask coord
//    select via wv_win=(curidx>>6)&3. Tournament + readfirstlane/readlane
//    chain deleted.
//  * cell[3] rotation: reset of buffer (p-1) post-barrier is separated by a
//    barrier from both its readers (prev iter) and next writers (iter+2).
//  * outputs stored straight to global by t0 (fire-and-forget), sres gone.
// Distance chain stays bit-exact (__fsub_rn/__fmul_rn/__fadd_rn, fminf,
// strict >, ascending j).
__global__ __launch_bounds__(256, 1) void fps_kernel(
    const float* __restrict__ pos, int* __restrict__ idx_i,
    float* __restrict__ idx_f, float* __restrict__ pos_s)
{
    __shared__ float4 scoord[2][4];
    __shared__ unsigned long long cell[3];
    const int b = blockIdx.x;
    const int t = threadIdx.x;
    const int wv = t >> 6;
    const int lane = t & 63;
    const float* posb = pos + (size_t)b * N_ * 3;

    float px[16], py[16], pz[16], dist[16];
#pragma unroll
    for (int j = 0; j < 16; ++j) {
        const int p = t + 256 * j;
        px[j] = posb[3 * p + 0];
        py[j] = posb[3 * p + 1];
        pz[j] = posb[3 * p + 2];
        dist[j] = 1e10f;
    }
    if (t < 3) cell[t] = 0ull;
    float ccx = posb[0], ccy = posb[1], ccz = posb[2];
    if (t == 0) {
        idx_i[b * NS_ + 0] = 0;
        idx_f[b * NS_ + 0] = 0.f;
        pos_s[(b * NS_ + 0) * 3 + 0] = ccx;
        pos_s[(b * NS_ + 0) * 3 + 1] = ccy;
        pos_s[(b * NS_ + 0) * 3 + 2] = ccz;
    }
    __syncthreads();                       // cell init visible

    int p = 1, pp = 0;                     // p = ns % 3, pp = prev p
    for (int ns = 1; ns < NS_; ++ns) {
        // ---- update dists + per-lane argmax w/ coord tracking ----
        float bv = -1.f; int bj = 0;
        float bx = px[0], by = py[0], bz = pz[0];
#pragma unroll
        for (int j = 0; j < 16; ++j) {
            float dx = __fsub_rn(px[j], ccx);
            float dy = __fsub_rn(py[j], ccy);
            float dz = __fsub_rn(pz[j], ccz);
            float d2 = __fadd_rn(__fadd_rn(__fmul_rn(dx, dx), __fmul_rn(dy, dy)), __fmul_rn(dz, dz));
            float dn = fminf(dist[j], d2);
            dist[j] = dn;
            bool g = dn > bv;             // strict > + ascending j => lowest idx on tie
            bv = g ? dn : bv;
            bj = g ? j : bj;
            bx = g ? px[j] : bx;
            by = g ? py[j] : by;
            bz = g ? pz[j] : bz;
        }
        // ---- wave fp32 max via DPP (result valid in lane 63) ----
        float wm = bv;
        DPP_FMAX_STEP(0x111, 0xF)   // row_shr:1
        DPP_FMAX_STEP(0x112, 0xF)   // row_shr:2
        DPP_FMAX_STEP(0x114, 0xF)   // row_shr:4
        DPP_FMAX_STEP(0x118, 0xF)   // row_shr:8
        DPP_FMAX_STEP(0x142, 0xA)   // row_bcast:15
        DPP_FMAX_STEP(0x143, 0xC)   // row_bcast:31
        const float wavemax = __uint_as_float(
            (unsigned)__builtin_amdgcn_readlane((int)__float_as_uint(wm), 63));
        // ---- branchless min-idx among max-achieving lanes (u32 max) ----
        const unsigned pidx = (unsigned)t + ((unsigned)bj << 8);   // global point idx
        unsigned cand = (bv == wavemax) ? (4096u - pidx) : 0u;
        DPP_UMAX_STEP(0x111, 0xF)
        DPP_UMAX_STEP(0x112, 0xF)
        DPP_UMAX_STEP(0x114, 0xF)
        DPP_UMAX_STEP(0x118, 0xF)
        DPP_UMAX_STEP(0x142, 0xA)
        DPP_UMAX_STEP(0x143, 0xC)
        const unsigned wcand = (unsigned)__builtin_amdgcn_readlane((int)cand, 63);
        const unsigned widx = 4096u - wcand;
        const int wl = (int)(widx & 63u);  // winner lane (point p lives in lane p&63)
        // ---- winner lane publishes coords; wave leader publishes key ----
        if (lane == wl)
            scoord[ns & 1][wv] = make_float4(bx, by, bz, 0.f);
        if (lane == 0) {
            const unsigned long long key =
                (((unsigned long long)__float_as_uint(wavemax)) << 32)
                | (unsigned long long)wcand;
            atomicMax(&cell[p], key);
        }
        __syncthreads();
        // ---- read cell + all 4 coord slots (parallel broadcasts) ----
        const unsigned long long k = cell[p];
        const float4 s0 = scoord[ns & 1][0];
        const float4 s1 = scoord[ns & 1][1];
        const float4 s2 = scoord[ns & 1][2];
        const float4 s3 = scoord[ns & 1][3];
        if (t == 0) cell[pp] = 0ull;       // reset: barrier-separated both ways
        const unsigned curidx = 4096u - (unsigned)(k & 0xFFFFFFFFull);
        const int wwin = (int)((curidx >> 6) & 3u);
        const bool w1 = (wwin & 1) != 0, w2 = (wwin & 2) != 0;
        float ax = w1 ? s1.x : s0.x, bx2 = w1 ? s3.x : s2.x;
        float ay = w1 ? s1.y : s0.y, by2 = w1 ? s3.y : s2.y;
        float az = w1 ? s1.z : s0.z, bz2 = w1 ? s3.z : s2.z;
        ccx = w2 ? bx2 : ax;
        ccy = w2 ? by2 : ay;
        ccz = w2 ? bz2 : az;
        if (t == 0) {
            idx_i[b * NS_ + ns] = (int)curidx;
            idx_f[b * NS_ + ns] = (float)curidx;
            pos_s[(b * NS_ + ns) * 3 + 0] = ccx;
            pos_s[(b * NS_ + ns) * 3 + 1] = ccy;
            pos_s[(b * NS_ + ns) * 3 + 2] = ccz;
        }
        pp = p; p = (p == 2) ? 0 : p + 1;
    }
}

// ---------------- radius-KNN v5: split-phase (d2-min DPP + ballot) --------
__global__ __launch_bounds__(256) void nbr_kernel(
    const float* __restrict__ pos, const float* __restrict__ pos_s,
    int* __restrict__ nbr, float* __restrict__ cntv)
{
    __shared__ unsigned long long ck[4][CAP_];
    const int w = threadIdx.x >> 6;
    const int lane = threadIdx.x & 63;
    const int s = blockIdx.x * 4 + w;
    const int b = s >> 10;
    const float cx = pos_s[s * 3 + 0], cy = pos_s[s * 3 + 1], cz = pos_s[s * 3 + 2];
    const float* posb = pos + (size_t)b * N_ * 3;
    int m = 0;
    for (int base = 0; base < N_; base += 64) {
        int p = base + lane;
        float dx = __fsub_rn(posb[3 * p + 0], cx);
        float dy = __fsub_rn(posb[3 * p + 1], cy);
        float dz = __fsub_rn(posb[3 * p + 2], cz);
        float d2 = __fadd_rn(__fadd_rn(__fmul_rn(dx, dx), __fmul_rn(dy, dy)), __fmul_rn(dz, dz));
        bool in = (d2 <= R2_);
        unsigned long long msk = __ballot(in);
        int before = __popcll(msk & ((1ull << lane) - 1ull));
        int slot = m + before;
        if (in && slot < CAP_)
            ck[w][slot] = ((unsigned long long)__float_as_uint(d2) << 32) | (unsigned)p;
        m += __popcll(msk);
    }
    if (m > CAP_) m = CAP_;
    __asm__ volatile("s_waitcnt lgkmcnt(0)" ::: "memory");
    int kcnt = m < K_ ? m : K_;
    if (m <= 256) {
        // register-resident candidates; selection = u64 local scan +
        // u32 d2-min DPP + ballot winner (exact idx-umin fallback on ties)
        unsigned long long kr[4];
#pragma unroll
        for (int r = 0; r < 4; ++r) {
            int q = r * 64 + lane;
            unsigned long long v = ck[w][q & (CAP_ - 1)];
            kr[r] = (q < m) ? v : ~0ull;
        }
        unsigned chosen = 0;
        for (int k = 0; k < kcnt; ++k) {
            unsigned long long localk = ~0ull; int br = -1;
#pragma unroll
            for (int r = 0; r < 4; ++r) {
                bool ok = (!((chosen >> r) & 1u)) && (kr[r] < localk);
                localk = ok ? kr[r] : localk;
                br = ok ? r : br;
            }
            const unsigned mybits = (unsigned)(localk >> 32);
            const unsigned myidx = (unsigned)localk;
            unsigned wb = mybits;
            DPP_UMIN_STEP_V(wb, 0x111, 0xF)
            DPP_UMIN_STEP_V(wb, 0x112, 0xF)
            DPP_UMIN_STEP_V(wb, 0x114, 0xF)
            DPP_UMIN_STEP_V(wb, 0x118, 0xF)
            DPP_UMIN_STEP_V(wb, 0x142, 0xA)
            DPP_UMIN_STEP_V(wb, 0x143, 0xC)
            const unsigned minbits = (unsigned)__builtin_amdgcn_readlane((int)wb, 63);
            const unsigned long long wmask = __ballot(mybits == minbits);
            unsigned widx;
            if (__popcll(wmask) == 1) {
                const int wl = __ffsll((long long)wmask) - 1;
                widx = (unsigned)__builtin_amdgcn_readlane((int)myidx, wl);
            } else {
                unsigned cand = (mybits == minbits) ? myidx : 0xFFFFFFFFu;
                DPP_UMIN_STEP(0x111, 0xF)
                DPP_UMIN_STEP(0x112, 0xF)
                DPP_UMIN_STEP(0x114, 0xF)
                DPP_UMIN_STEP(0x118, 0xF)
                DPP_UMIN_STEP(0x142, 0xA)
                DPP_UMIN_STEP(0x143, 0xC)
                widx = (unsigned)__builtin_amdgcn_readlane((int)cand, 63);
            }
            if (mybits == minbits && myidx == widx) chosen |= 1u << br;
            if (lane == 0) nbr[s * K_ + k] = (int)widx;
        }
    } else {
        // exact fallback (rare): LDS-scan selection with u64 DPP min
        unsigned chosen = 0;
        for (int k = 0; k < kcnt; ++k) {
            unsigned long long localk = ~0ull; int bslot = -1;
            for (int r = 0; r * 64 + lane < m; ++r) {
                if (chosen & (1u << r)) continue;
                int q = r * 64 + lane;
                unsigned long long key = ck[w][q];
                if (key < localk) { localk = key; bslot = q; }
            }
            unsigned kh = (unsigned)(localk >> 32), kl = (unsigned)localk;
#define DPP_MIN_STEP2(CTRL, RM)                                           \
            {                                                             \
                unsigned nh = dppmov<CTRL, RM>(kh);                       \
                unsigned nl = dppmov<CTRL, RM>(kl);                       \
                unsigned long long nk = (((unsigned long long)nh) << 32) | nl; \
                unsigned long long ok = (((unsigned long long)kh) << 32) | kl; \
                if (nk < ok) { kh = nh; kl = nl; }                        \
            }
            DPP_MIN_STEP2(0x111, 0xF)
            DPP_MIN_STEP2(0x112, 0xF)
            DPP_MIN_STEP2(0x114, 0xF)
            DPP_MIN_STEP2(0x118, 0xF)
            DPP_MIN_STEP2(0x142, 0xA)
            DPP_MIN_STEP2(0x143, 0xC)
#undef DPP_MIN_STEP2
            unsigned mh = (unsigned)__builtin_amdgcn_readlane((int)kh, 63);
            unsigned ml = (unsigned)__builtin_amdgcn_readlane((int)kl, 63);
            unsigned long long bk = (((unsigned long long)mh) << 32) | ml;
            if (localk == bk && bslot >= 0) chosen |= 1u << (bslot >> 6);
            if (lane == 0) nbr[s * K_ + k] = (int)(bk & 0xFFFFFFFFull);
        }
    }
    if (lane == 0) {
        for (int k = kcnt; k < K_; ++k) nbr[s * K_ + k] = -1;
        cntv[s] = (float)kcnt;
    }
}

// ---------------- message MLP v5: bf16 MFMA, pre-converted x ----------------
__global__ __launch_bounds__(256) void msg_kernel(
    const ushort_t* __restrict__ xb, const float* __restrict__ pos,
    const float* __restrict__ W1, const float* __restrict__ b1,
    const float* __restrict__ W2, const float* __restrict__ b2,
    const float* __restrict__ pos_s, const int* __restrict__ nbr,
    const float* __restrict__ cntv, float* __restrict__ aggr_x,
    float* __restrict__ out_pos)
{
    __shared__ __align__(16) char smem[4 * 5120];
    const int t = threadIdx.x;
    const int wv = t >> 6, lane = t & 63;
    const int quad = lane >> 4, cl = lane & 15;
    char* wb = smem + wv * 5120;

    short8 bfrag[8][2];
    float b1v[8], w1dv[8], w2v0[8], w2v1[8], w2v2[8];
#pragma unroll
    for (int Nt = 0; Nt < 8; ++Nt) {
        const int h = Nt * 16 + cl;
#pragma unroll
        for (int ks = 0; ks < 2; ++ks) {
            short8 f;
#pragma unroll
            for (int jj = 0; jj < 8; ++jj)
                f[jj] = f2bf(W1[(ks * 32 + quad * 8 + jj) * H_ + h]);
            bfrag[Nt][ks] = f;
        }
        b1v[Nt] = b1[h];
        w1dv[Nt] = W1[64 * H_ + h];
        w2v0[Nt] = W2[h * 3 + 0];
        w2v1[Nt] = W2[h * 3 + 1];
        w2v2[Nt] = W2[h * 3 + 2];
    }
    const float b20 = b2[0], b21 = b2[1], b22 = b2[2];

    const int kkg = lane >> 1, half = lane & 1;
    for (int i = 0; i < 4; ++i) {
        const int s = blockIdx.x * 16 + wv * 4 + i;
        const int b = s >> 10;
        const int n = nbr[s * K_ + kkg];
        {
            char* frow = wb + kkg * 144 + half * 64;
            if (n >= 0) {
                const short8* xr = (const short8*)(xb + ((size_t)b * N_ + n) * D_) + half * 4;
#pragma unroll
                for (int q = 0; q < 4; ++q) *(short8*)(frow + q * 16) = xr[q];
            } else {
                short8 z = {0, 0, 0, 0, 0, 0, 0, 0};
#pragma unroll
                for (int q = 0; q < 4; ++q) *(short8*)(frow + q * 16) = z;
            }
            if (half == 0) {
                float dxm = 0.f, dym = 0.f, dzm = 0.f, de = -1.f;
                if (n >= 0) {
                    const float* pj = pos + ((size_t)b * N_ + n) * 3;
                    float dx = pj[0] - pos_s[s * 3 + 0];
                    float dy = pj[1] - pos_s[s * 3 + 1];
                    float dz = pj[2] - pos_s[s * 3 + 2];
                    float d2 = dx * dx + dy * dy + dz * dz;
                    de = d2 > 0.f ? sqrtf(d2) : 0.f;
                    dxm = dx; dym = dy; dzm = dz;
                }
                f32x4 sv = {dxm, dym, dzm, de};
                *(f32x4*)(wb + 4608 + kkg * 16) = sv;
            }
        }
        float agp[8] = {0, 0, 0, 0, 0, 0, 0, 0};
        float gp0[8] = {0, 0, 0, 0, 0, 0, 0, 0};
        float gp1[8] = {0, 0, 0, 0, 0, 0, 0, 0};
        float gp2[8] = {0, 0, 0, 0, 0, 0, 0, 0};
#pragma unroll
        for (int Mt = 0; Mt < 2; ++Mt) {
            short8 a0 = *(short8*)(wb + (Mt * 16 + cl) * 144 + quad * 16);
            short8 a1 = *(short8*)(wb + (Mt * 16 + cl) * 144 + 64 + quad * 16);
            f32x4 acc[8];
#pragma unroll
            for (int Nt = 0; Nt < 8; ++Nt) {
                f32x4 z = {0.f, 0.f, 0.f, 0.f};
                z = __builtin_amdgcn_mfma_f32_16x16x32_bf16(a0, bfrag[Nt][0], z, 0, 0, 0);
                z = __builtin_amdgcn_mfma_f32_16x16x32_bf16(a1, bfrag[Nt][1], z, 0, 0, 0);
                acc[Nt] = z;
            }
            f32x4 sd[4];
#pragma unroll
            for (int r = 0; r < 4; ++r)
                sd[r] = *(f32x4*)(wb + 4608 + (Mt * 16 + quad * 4 + r) * 16);
#pragma unroll
            for (int Nt = 0; Nt < 8; ++Nt) {
#pragma unroll
                for (int r = 0; r < 4; ++r) {
                    float dr = sd[r][3];
                    float wgt = dr >= 0.f ? 1.f : 0.f;
                    float dd = dr >= 0.f ? dr : 0.f;
                    float e = fmaf(dd, w1dv[Nt], acc[Nt][r]) + b1v[Nt];
                    e = e > 0.f ? e : 0.f;
                    agp[Nt] = fmaf(wgt, e, agp[Nt]);
                    gp0[Nt] = fmaf(sd[r][0], e, gp0[Nt]);
                    gp1[Nt] = fmaf(sd[r][1], e, gp1[Nt]);
                    gp2[Nt] = fmaf(sd[r][2], e, gp2[Nt]);
                }
            }
        }
#pragma unroll
        for (int Nt = 0; Nt < 8; ++Nt) {
            float v = agp[Nt]; v += __shfl_xor(v, 16); v += __shfl_xor(v, 32);
            aggr_x[(size_t)s * H_ + Nt * 16 + cl] = v;
            float g0 = gp0[Nt]; g0 += __shfl_xor(g0, 16); g0 += __shfl_xor(g0, 32); gp0[Nt] = g0;
            float g1 = gp1[Nt]; g1 += __shfl_xor(g1, 16); g1 += __shfl_xor(g1, 32); gp1[Nt] = g1;
            float g2 = gp2[Nt]; g2 += __shfl_xor(g2, 16); g2 += __shfl_xor(g2, 32); gp2[Nt] = g2;
        }
        float pr0 = 0.f, pr1 = 0.f, pr2 = 0.f;
#pragma unroll
        for (int Nt = 0; Nt < 8; ++Nt) {
            pr0 = fmaf(w2v0[Nt], gp0[Nt], pr0);
            pr1 = fmaf(w2v1[Nt], gp1[Nt], pr1);
            pr2 = fmaf(w2v2[Nt], gp2[Nt], pr2);
        }
#pragma unroll
        for (int off = 1; off < 16; off <<= 1) {
            pr0 += __shfl_xor(pr0, off);
            pr1 += __shfl_xor(pr1, off);
            pr2 += __shfl_xor(pr2, off);
        }
        f32x4 dsv = *(f32x4*)(wb + 4608 + (lane & 31) * 16);
        float q0 = dsv[0], q1 = dsv[1], q2 = dsv[2];
#pragma unroll
        for (int off = 1; off < 32; off <<= 1) {
            q0 += __shfl_xor(q0, off);
            q1 += __shfl_xor(q1, off);
            q2 += __shfl_xor(q2, off);
        }
        float cnt = cntv[s]; if (cnt < 1.f) cnt = 1.f;
        if (lane < 3) {
            float pr = lane == 0 ? pr0 : (lane == 1 ? pr1 : pr2);
            float qq = lane == 0 ? q0 : (lane == 1 ? q1 : q2);
            float bb = lane == 0 ? b20 : (lane == 1 ? b21 : b22);
            out_pos[s * 3 + lane] = pos_s[s * 3 + lane] + (pr + bb * qq) / cnt;
        }
    }
}

// ---------------- update GEMM: relu([x_d, aggr_x] @ W3 + b3) ----------------
__global__ __launch_bounds__(128) void out_kernel(
    const float* __restrict__ x, const float* __restrict__ W3,
    const float* __restrict__ b3, const int* __restrict__ idx_i,
    const float* __restrict__ aggr_x, float* __restrict__ out_x)
{
    __shared__ float rows[32][208];
    const int t = threadIdx.x;
    const int s0 = blockIdx.x * 32;
    const int sl = t >> 2, part = t & 3;
    const int s = s0 + sl;
    const int b = s >> 10;
    const int id = idx_i[s];
    {
        const float4* xr = (const float4*)(x + ((size_t)b * N_ + id) * D_);
        float4* rr = (float4*)&rows[sl][0];
#pragma unroll
        for (int q = 0; q < 4; ++q) rr[part * 4 + q] = xr[part * 4 + q];
        const float4* ar = (const float4*)(aggr_x + (size_t)s * H_);
        float4* rr2 = (float4*)&rows[sl][64];
#pragma unroll
        for (int q = 0; q < 8; ++q) rr2[part * 8 + q] = ar[part * 8 + q];
    }
    __syncthreads();
    float acc[32];
#pragma unroll
    for (int i = 0; i < 32; ++i) acc[i] = 0.f;
    for (int j4 = 0; j4 < 48; ++j4) {
        float w0 = W3[(j4 * 4 + 0) * H_ + t];
        float w1 = W3[(j4 * 4 + 1) * H_ + t];
        float w2 = W3[(j4 * 4 + 2) * H_ + t];
        float w3 = W3[(j4 * 4 + 3) * H_ + t];
#pragma unroll
        for (int i = 0; i < 32; ++i) {
            const float4 f = *(const float4*)&rows[i][j4 * 4];
            float a = acc[i];
            a = fmaf(f.x, w0, a); a = fmaf(f.y, w1, a);
            a = fmaf(f.z, w2, a); a = fmaf(f.w, w3, a);
            acc[i] = a;
        }
    }
    const float bb = b3[t];
#pragma unroll
    for (int i = 0; i < 32; ++i) {
        float v = acc[i] + bb;
        v = v > 0.f ? v : 0.f;
        out_x[(size_t)(s0 + i) * H_ + t] = v;
    }
}

extern "C" void kernel_launch(void* const* d_in, const int* in_sizes, int n_in,
                              void* d_out, int out_size, void* d_ws, size_t ws_size,
                              hipStream_t stream) {
    const float* x   = (const float*)d_in[0];
    const float* pos = (const float*)d_in[1];
    const float* W1  = (const float*)d_in[2];
    const float* b1  = (const float*)d_in[3];
    const float* W2  = (const float*)d_in[4];
    const float* b2  = (const float*)d_in[5];
    const float* W3  = (const float*)d_in[6];
    const float* b3  = (const float*)d_in[7];

    float* out_x   = (float*)d_out;                       // [16,1024,128]
    float* out_pos = (float*)d_out + 2097152;             // [16,1024,3]
    float* idx_f   = (float*)d_out + 2146304;             // [16,1024] as float

    char* ws = (char*)d_ws;
    int*      idx_i  = (int*)ws;                   // 16384 ints
    float*    pos_s  = (float*)(ws + 65536);       // 49152 floats
    int*      nbr    = (int*)(ws + 262144);        // 524288 ints
    float*    cntv   = (float*)(ws + 2359296);     // 16384 floats
    float*    aggr_x = (float*)(ws + 2424832);     // 2097152 floats
    ushort_t* x_bf16 = (ushort_t*)(ws + 10813440); // 16777216 ushorts (ends ~19.2MB)

    cvt_kernel<<<(B_ * N_ * D_) / (256 * 8), 256, 0, stream>>>(x, x_bf16);
    fps_kernel<<<B_, 256, 0, stream>>>(pos, idx_i, idx_f, pos_s);
    nbr_kernel<<<(B_ * NS_) / 4, 256, 0, stream>>>(pos, pos_s, nbr, cntv);
    msg_kernel<<<(B_ * NS_) / 16, 256, 0, stream>>>(x_bf16, pos, W1, b1, W2, b2,
                                                    pos_s, nbr, cntv, aggr_x, out_pos);
    out_kernel<<<(B_ * NS_) / 32, 128, 0, stream>>>(x, W3, b3, idx_i, aggr_x, out_x);
}

// Round 4
// 1189.265 us; speedup vs baseline: 1.0131x; 1.0131x over previous
//
#include <hip/hip_runtime.h>
#include <math.h>

#define B_ 16
#define N_ 4096
#define D_ 64
#define H_ 128
#define K_ 32
#define NS_ 1024
#define R2_ 0.04f
#define CAP_ 1024

typedef short short8 __attribute__((ext_vector_type(8)));
typedef float f32x4 __attribute__((ext_vector_type(4)));
typedef float f32x2 __attribute__((ext_vector_type(2)));
typedef unsigned short ushort_t;

static __device__ __forceinline__ short f2bf(float f) {
    unsigned u = __float_as_uint(f);
    unsigned r = (u + 0x7FFFu + ((u >> 16) & 1u)) >> 16;   // round-to-nearest-even
    return (short)r;
}

template<int CTRL, int RM>
static __device__ __forceinline__ unsigned dppmov(unsigned v) {
    // old = v -> masked/invalid lanes keep v (identity for max/min)
    return (unsigned)__builtin_amdgcn_update_dpp((int)v, (int)v, CTRL, RM, 0xF, false);
}

#define DPP_FMAX_STEP(CTRL, RM)                                           \
    {                                                                     \
        float n = __uint_as_float(dppmov<CTRL, RM>(__float_as_uint(wm))); \
        wm = fmaxf(wm, n);                                                \
    }

#define DPP_UMIN_STEP(CTRL, RM)                                           \
    {                                                                     \
        unsigned n = dppmov<CTRL, RM>(cand);                              \
        cand = n < cand ? n : cand;                                       \
    }

#define DPP_UMIN_STEP_V(var, CTRL, RM)                                    \
    {                                                                     \
        unsigned n = dppmov<CTRL, RM>(var);                               \
        var = n < var ? n : var;                                          \
    }

// ---------------- x -> bf16 pre-convert (RNE, identical to f2bf) ----------
__global__ __launch_bounds__(256) void cvt_kernel(
    const float* __restrict__ x, ushort_t* __restrict__ xb)
{
    const size_t i = ((size_t)blockIdx.x * 256 + threadIdx.x) * 8;
    float4 a = *(const float4*)(x + i);
    float4 c = *(const float4*)(x + i + 4);
    short8 o;
    o[0] = f2bf(a.x); o[1] = f2bf(a.y); o[2] = f2bf(a.z); o[3] = f2bf(a.w);
    o[4] = f2bf(c.x); o[5] = f2bf(c.y); o[6] = f2bf(c.z); o[7] = f2bf(c.w);
    *(short8*)(xb + i) = o;
}

// ---------------- FPS v12: v8 skeleton + dist-loop micro-opt ---------------
// v8 (647us, best measured) tail kept BYTE-IDENTICAL (ballot fast-path +
// readlane-carried 4-slot tournament). Only the distance-update changes:
//  * packed-f32 d2: arithmetic on float2 ext-vectors with fp contract(off)
//    -> backend can emit v_pk_mul_f32/v_pk_add_f32 (same RN mul/add op
//    sequence as the old __fmul_rn/__fadd_rn chain => bit-identical d2;
//    scalarization fallback is also bit-identical). ~96->~48 arith instrs.
//  * tree argmax (4-level tournament, strict > for the higher index =>
//    lowest index on exact ties, same selection as the serial scan) cuts
//    the dependent chain from depth 16 to depth 4 at 1 wave/SIMD.
__global__ __launch_bounds__(256, 1) void fps_kernel(
    const float* __restrict__ pos, int* __restrict__ idx_i,
    float* __restrict__ idx_f, float* __restrict__ pos_s)
{
    __shared__ float4 lpos4[N_];                         // 64 KB
    __shared__ float4 sres[NS_];                         // 16 KB
    __shared__ unsigned long long skey[2][4];
    __shared__ float4 scoord[2][4];
    const int b = blockIdx.x;
    const int t = threadIdx.x;
    const int wv = t >> 6;
    const int lane = t & 63;
    const float* posb = pos + (size_t)b * N_ * 3;
    for (int p = t; p < N_; p += 256)
        lpos4[p] = make_float4(posb[3 * p + 0], posb[3 * p + 1], posb[3 * p + 2], 0.f);
    __syncthreads();

    f32x2 pxv[8], pyv[8], pzv[8];
    float dist_[16];
#pragma unroll
    for (int j = 0; j < 16; ++j) {
        float4 v = lpos4[t + 256 * j];
        pxv[j >> 1][j & 1] = v.x;
        pyv[j >> 1][j & 1] = v.y;
        pzv[j >> 1][j & 1] = v.z;
        dist_[j] = 1e10f;
    }
    unsigned curidx = 0;
    float4 c0 = lpos4[0];
    float ccx = c0.x, ccy = c0.y, ccz = c0.z;

    for (int ns = 0; ns < NS_; ++ns) {
        if (t == 0)
            sres[ns] = make_float4(ccx, ccy, ccz, __uint_as_float(curidx));
        // ---- packed d2 + running-min update (bit-exact vs scalar chain) ----
        float dn[16];
        {
#pragma clang fp contract(off)
            const f32x2 cx2 = {ccx, ccx}, cy2 = {ccy, ccy}, cz2 = {ccz, ccz};
#pragma unroll
            for (int q = 0; q < 8; ++q) {
                f32x2 dx = pxv[q] - cx2;
                f32x2 dy = pyv[q] - cy2;
                f32x2 dz = pzv[q] - cz2;
                f32x2 d2 = (dx * dx + dy * dy) + dz * dz;   // mul,mul,add,mul,add (RN)
                float m0 = fminf(dist_[2 * q + 0], d2[0]);
                float m1 = fminf(dist_[2 * q + 1], d2[1]);
                dist_[2 * q + 0] = m0;
                dist_[2 * q + 1] = m1;
                dn[2 * q + 0] = m0;
                dn[2 * q + 1] = m1;
            }
        }
        // ---- tree argmax: strict > for higher index => lowest idx on tie ----
        float tv8[8]; int tj8[8];
#pragma unroll
        for (int k = 0; k < 8; ++k) {
            bool g = dn[2 * k + 1] > dn[2 * k];
            tv8[k] = g ? dn[2 * k + 1] : dn[2 * k];
            tj8[k] = g ? 2 * k + 1 : 2 * k;
        }
        float tv4[4]; int tj4[4];
#pragma unroll
        for (int k = 0; k < 4; ++k) {
            bool g = tv8[2 * k + 1] > tv8[2 * k];
            tv4[k] = g ? tv8[2 * k + 1] : tv8[2 * k];
            tj4[k] = g ? tj8[2 * k + 1] : tj8[2 * k];
        }
        float tv2[2]; int tj2[2];
#pragma unroll
        for (int k = 0; k < 2; ++k) {
            bool g = tv4[2 * k + 1] > tv4[2 * k];
            tv2[k] = g ? tv4[2 * k + 1] : tv4[2 * k];
            tj2[k] = g ? tj4[2 * k + 1] : tj4[2 * k];
        }
        const bool gf = tv2[1] > tv2[0];
        const float bv = gf ? tv2[1] : tv2[0];
        const int bj = gf ? tj2[1] : tj2[0];
        // ---- wave fp32 max via DPP (result valid in lane 63) ----
        float wm = bv;
        DPP_FMAX_STEP(0x111, 0xF)   // row_shr:1
        DPP_FMAX_STEP(0x112, 0xF)   // row_shr:2
        DPP_FMAX_STEP(0x114, 0xF)   // row_shr:4
        DPP_FMAX_STEP(0x118, 0xF)   // row_shr:8
        DPP_FMAX_STEP(0x142, 0xA)   // row_bcast:15
        DPP_FMAX_STEP(0x143, 0xC)   // row_bcast:31
        const float wavemax = __uint_as_float(
            (unsigned)__builtin_amdgcn_readlane((int)__float_as_uint(wm), 63));
        // ---- min global idx among max-achieving lanes ----
        const unsigned pidx = (unsigned)t + ((unsigned)bj << 8);   // == global point idx
        const unsigned long long mask = __ballot(bv == wavemax);
        unsigned widx;
        if (__popcll(mask) == 1) {             // unique winner (common case)
            const int wl = __ffsll((long long)mask) - 1;
            widx = (unsigned)__builtin_amdgcn_readlane((int)pidx, wl);
        } else {                                // exact tie fallback
            unsigned cand = (bv == wavemax) ? pidx : 0xFFFFFFFFu;
            DPP_UMIN_STEP(0x111, 0xF)
            DPP_UMIN_STEP(0x112, 0xF)
            DPP_UMIN_STEP(0x114, 0xF)
            DPP_UMIN_STEP(0x118, 0xF)
            DPP_UMIN_STEP(0x142, 0xA)
            DPP_UMIN_STEP(0x143, 0xC)
            widx = (unsigned)__builtin_amdgcn_readlane((int)cand, 63);
        }
        // prefetch this wave's winner coords (broadcast, uniform addr) so the
        // coord fetch latency hides under the key store + barrier wait
        float4 wc = lpos4[widx];
        if (lane == 0) {
            skey[ns & 1][wv] = (((unsigned long long)__float_as_uint(wavemax)) << 32)
                             | (unsigned long long)(0xFFFFFFFFu - widx);
            scoord[ns & 1][wv] = wc;
        }
        __syncthreads();
        // ---- 4-slot u64-max tournament (carrying slot id); coords via
        //      v_readlane from the slot-holder lane (no second LDS read) ----
        {
            unsigned sid = (unsigned)(lane & 3);
            unsigned long long skv = skey[ns & 1][sid];
            float4 scv = scoord[ns & 1][sid];
            unsigned kh2 = (unsigned)(skv >> 32), kl2 = (unsigned)skv;
#define SLOT_STEP(CTRL)                                                        \
            {                                                                  \
                unsigned nh = dppmov<CTRL, 0xF>(kh2);                          \
                unsigned nl = dppmov<CTRL, 0xF>(kl2);                          \
                unsigned nsid = dppmov<CTRL, 0xF>(sid);                        \
                unsigned long long nk = (((unsigned long long)nh) << 32) | nl; \
                unsigned long long ok = (((unsigned long long)kh2) << 32) | kl2;\
                if (nk > ok) { kh2 = nh; kl2 = nl; sid = nsid; }               \
            }
            SLOT_STEP(0x101)   // row_shl:1
            SLOT_STEP(0x102)   // row_shl:2
#undef SLOT_STEP
            const int slotwin = __builtin_amdgcn_readfirstlane((int)sid);
            curidx = 0xFFFFFFFFu - (unsigned)__builtin_amdgcn_readfirstlane((int)kl2);
            ccx = __uint_as_float((unsigned)__builtin_amdgcn_readlane(
                      (int)__float_as_uint(scv.x), slotwin));
            ccy = __uint_as_float((unsigned)__builtin_amdgcn_readlane(
                      (int)__float_as_uint(scv.y), slotwin));
            ccz = __uint_as_float((unsigned)__builtin_amdgcn_readlane(
                      (int)__float_as_uint(scv.z), slotwin));
        }
    }
    __syncthreads();
    for (int i = t; i < NS_; i += 256) {
        float4 r = sres[i];
        unsigned id = __float_as_uint(r.w);
        idx_i[b * NS_ + i] = (int)id;
        idx_f[b * NS_ + i] = (float)id;
        pos_s[(b * NS_ + i) * 3 + 0] = r.x;
        pos_s[(b * NS_ + i) * 3 + 1] = r.y;
        pos_s[(b * NS_ + i) * 3 + 2] = r.z;
    }
}

// ---------------- radius-KNN v5: split-phase (d2-min DPP + ballot) --------
__global__ __launch_bounds__(256) void nbr_kernel(
    const float* __restrict__ pos, const float* __restrict__ pos_s,
    int* __restrict__ nbr, float* __restrict__ cntv)
{
    __shared__ unsigned long long ck[4][CAP_];
    const int w = threadIdx.x >> 6;
    const int lane = threadIdx.x & 63;
    const int s = blockIdx.x * 4 + w;
    const int b = s >> 10;
    const float cx = pos_s[s * 3 + 0], cy = pos_s[s * 3 + 1], cz = pos_s[s * 3 + 2];
    const float* posb = pos + (size_t)b * N_ * 3;
    int m = 0;
    for (int base = 0; base < N_; base += 64) {
        int p = base + lane;
        float dx = __fsub_rn(posb[3 * p + 0], cx);
        float dy = __fsub_rn(posb[3 * p + 1], cy);
        float dz = __fsub_rn(posb[3 * p + 2], cz);
        float d2 = __fadd_rn(__fadd_rn(__fmul_rn(dx, dx), __fmul_rn(dy, dy)), __fmul_rn(dz, dz));
        bool in = (d2 <= R2_);
        unsigned long long msk = __ballot(in);
        int before = __popcll(msk & ((1ull << lane) - 1ull));
        int slot = m + before;
        if (in && slot < CAP_)
            ck[w][slot] = ((unsigned long long)__float_as_uint(d2) << 32) | (unsigned)p;
        m += __popcll(msk);
    }
    if (m > CAP_) m = CAP_;
    __asm__ volatile("s_waitcnt lgkmcnt(0)" ::: "memory");
    int kcnt = m < K_ ? m : K_;
    if (m <= 256) {
        // register-resident candidates; selection = u64 local scan +
        // u32 d2-min DPP + ballot winner (exact idx-umin fallback on ties)
        unsigned long long kr[4];
#pragma unroll
        for (int r = 0; r < 4; ++r) {
            int q = r * 64 + lane;
            unsigned long long v = ck[w][q & (CAP_ - 1)];
            kr[r] = (q < m) ? v : ~0ull;
        }
        unsigned chosen = 0;
        for (int k = 0; k < kcnt; ++k) {
            unsigned long long localk = ~0ull; int br = -1;
#pragma unroll
            for (int r = 0; r < 4; ++r) {
                bool ok = (!((chosen >> r) & 1u)) && (kr[r] < localk);
                localk = ok ? kr[r] : localk;
                br = ok ? r : br;
            }
            const unsigned mybits = (unsigned)(localk >> 32);
            const unsigned myidx = (unsigned)localk;
            unsigned wb = mybits;
            DPP_UMIN_STEP_V(wb, 0x111, 0xF)
            DPP_UMIN_STEP_V(wb, 0x112, 0xF)
            DPP_UMIN_STEP_V(wb, 0x114, 0xF)
            DPP_UMIN_STEP_V(wb, 0x118, 0xF)
            DPP_UMIN_STEP_V(wb, 0x142, 0xA)
            DPP_UMIN_STEP_V(wb, 0x143, 0xC)
            const unsigned minbits = (unsigned)__builtin_amdgcn_readlane((int)wb, 63);
            const unsigned long long wmask = __ballot(mybits == minbits);
            unsigned widx;
            if (__popcll(wmask) == 1) {
                const int wl = __ffsll((long long)wmask) - 1;
                widx = (unsigned)__builtin_amdgcn_readlane((int)myidx, wl);
            } else {
                unsigned cand = (mybits == minbits) ? myidx : 0xFFFFFFFFu;
                DPP_UMIN_STEP(0x111, 0xF)
                DPP_UMIN_STEP(0x112, 0xF)
                DPP_UMIN_STEP(0x114, 0xF)
                DPP_UMIN_STEP(0x118, 0xF)
                DPP_UMIN_STEP(0x142, 0xA)
                DPP_UMIN_STEP(0x143, 0xC)
                widx = (unsigned)__builtin_amdgcn_readlane((int)cand, 63);
            }
            if (mybits == minbits && myidx == widx) chosen |= 1u << br;
            if (lane == 0) nbr[s * K_ + k] = (int)widx;
        }
    } else {
        // exact fallback (rare): LDS-scan selection with u64 DPP min
        unsigned chosen = 0;
        for (int k = 0; k < kcnt; ++k) {
            unsigned long long localk = ~0ull; int bslot = -1;
            for (int r = 0; r * 64 + lane < m; ++r) {
                if (chosen & (1u << r)) continue;
                int q = r * 64 + lane;
                unsigned long long key = ck[w][q];
                if (key < localk) { localk = key; bslot = q; }
            }
            unsigned kh = (unsigned)(localk >> 32), kl = (unsigned)localk;
#define DPP_MIN_STEP2(CTRL, RM)                                           \
            {                                                             \
                unsigned nh = dppmov<CTRL, RM>(kh);                       \
                unsigned nl = dppmov<CTRL, RM>(kl);                       \
                unsigned long long nk = (((unsigned long long)nh) << 32) | nl; \
                unsigned long long ok = (((unsigned long long)kh) << 32) | kl; \
                if (nk < ok) { kh = nh; kl = nl; }                        \
            }
            DPP_MIN_STEP2(0x111, 0xF)
            DPP_MIN_STEP2(0x112, 0xF)
            DPP_MIN_STEP2(0x114, 0xF)
            DPP_MIN_STEP2(0x118, 0xF)
            DPP_MIN_STEP2(0x142, 0xA)
            DPP_MIN_STEP2(0x143, 0xC)
#undef DPP_MIN_STEP2
            unsigned mh = (unsigned)__builtin_amdgcn_readlane((int)kh, 63);
            unsigned ml = (unsigned)__builtin_amdgcn_readlane((int)kl, 63);
            unsigned long long bk = (((unsigned long long)mh) << 32) | ml;
            if (localk == bk && bslot >= 0) chosen |= 1u << (bslot >> 6);
            if (lane == 0) nbr[s * K_ + k] = (int)(bk & 0xFFFFFFFFull);
        }
    }
    if (lane == 0) {
        for (int k = kcnt; k < K_; ++k) nbr[s * K_ + k] = -1;
        cntv[s] = (float)kcnt;
    }
}

// ---------------- message MLP v5: bf16 MFMA, pre-converted x ----------------
__global__ __launch_bounds__(256) void msg_kernel(
    const ushort_t* __restrict__ xb, const float* __restrict__ pos,
    const float* __restrict__ W1, const float* __restrict__ b1,
    const float* __restrict__ W2, const float* __restrict__ b2,
    const float* __restrict__ pos_s, const int* __restrict__ nbr,
    const float* __restrict__ cntv, float* __restrict__ aggr_x,
    float* __restrict__ out_pos)
{
    __shared__ __align__(16) char smem[4 * 5120];
    const int t = threadIdx.x;
    const int wv = t >> 6, lane = t & 63;
    const int quad = lane >> 4, cl = lane & 15;
    char* wb = smem + wv * 5120;

    short8 bfrag[8][2];
    float b1v[8], w1dv[8], w2v0[8], w2v1[8], w2v2[8];
#pragma unroll
    for (int Nt = 0; Nt < 8; ++Nt) {
        const int h = Nt * 16 + cl;
#pragma unroll
        for (int ks = 0; ks < 2; ++ks) {
            short8 f;
#pragma unroll
            for (int jj = 0; jj < 8; ++jj)
                f[jj] = f2bf(W1[(ks * 32 + quad * 8 + jj) * H_ + h]);
            bfrag[Nt][ks] = f;
        }
        b1v[Nt] = b1[h];
        w1dv[Nt] = W1[64 * H_ + h];
        w2v0[Nt] = W2[h * 3 + 0];
        w2v1[Nt] = W2[h * 3 + 1];
        w2v2[Nt] = W2[h * 3 + 2];
    }
    const float b20 = b2[0], b21 = b2[1], b22 = b2[2];

    const int kkg = lane >> 1, half = lane & 1;
    for (int i = 0; i < 4; ++i) {
        const int s = blockIdx.x * 16 + wv * 4 + i;
        const int b = s >> 10;
        const int n = nbr[s * K_ + kkg];
        {
            char* frow = wb + kkg * 144 + half * 64;
            if (n >= 0) {
                const short8* xr = (const short8*)(xb + ((size_t)b * N_ + n) * D_) + half * 4;
#pragma unroll
                for (int q = 0; q < 4; ++q) *(short8*)(frow + q * 16) = xr[q];
            } else {
                short8 z = {0, 0, 0, 0, 0, 0, 0, 0};
#pragma unroll
                for (int q = 0; q < 4; ++q) *(short8*)(frow + q * 16) = z;
            }
            if (half == 0) {
                float dxm = 0.f, dym = 0.f, dzm = 0.f, de = -1.f;
                if (n >= 0) {
                    const float* pj = pos + ((size_t)b * N_ + n) * 3;
                    float dx = pj[0] - pos_s[s * 3 + 0];
                    float dy = pj[1] - pos_s[s * 3 + 1];
                    float dz = pj[2] - pos_s[s * 3 + 2];
                    float d2 = dx * dx + dy * dy + dz * dz;
                    de = d2 > 0.f ? sqrtf(d2) : 0.f;
                    dxm = dx; dym = dy; dzm = dz;
                }
                f32x4 sv = {dxm, dym, dzm, de};
                *(f32x4*)(wb + 4608 + kkg * 16) = sv;
            }
        }
        float agp[8] = {0, 0, 0, 0, 0, 0, 0, 0};
        float gp0[8] = {0, 0, 0, 0, 0, 0, 0, 0};
        float gp1[8] = {0, 0, 0, 0, 0, 0, 0, 0};
        float gp2[8] = {0, 0, 0, 0, 0, 0, 0, 0};
#pragma unroll
        for (int Mt = 0; Mt < 2; ++Mt) {
            short8 a0 = *(short8*)(wb + (Mt * 16 + cl) * 144 + quad * 16);
            short8 a1 = *(short8*)(wb + (Mt * 16 + cl) * 144 + 64 + quad * 16);
            f32x4 acc[8];
#pragma unroll
            for (int Nt = 0; Nt < 8; ++Nt) {
                f32x4 z = {0.f, 0.f, 0.f, 0.f};
                z = __builtin_amdgcn_mfma_f32_16x16x32_bf16(a0, bfrag[Nt][0], z, 0, 0, 0);
                z = __builtin_amdgcn_mfma_f32_16x16x32_bf16(a1, bfrag[Nt][1], z, 0, 0, 0);
                acc[Nt] = z;
            }
            f32x4 sd[4];
#pragma unroll
            for (int r = 0; r < 4; ++r)
                sd[r] = *(f32x4*)(wb + 4608 + (Mt * 16 + quad * 4 + r) * 16);
#pragma unroll
            for (int Nt = 0; Nt < 8; ++Nt) {
#pragma unroll
                for (int r = 0; r < 4; ++r) {
                    float dr = sd[r][3];
                    float wgt = dr >= 0.f ? 1.f : 0.f;
                    float dd = dr >= 0.f ? dr : 0.f;
                    float e = fmaf(dd, w1dv[Nt], acc[Nt][r]) + b1v[Nt];
                    e = e > 0.f ? e : 0.f;
                    agp[Nt] = fmaf(wgt, e, agp[Nt]);
                    gp0[Nt] = fmaf(sd[r][0], e, gp0[Nt]);
                    gp1[Nt] = fmaf(sd[r][1], e, gp1[Nt]);
                    gp2[Nt] = fmaf(sd[r][2], e, gp2[Nt]);
                }
            }
        }
#pragma unroll
        for (int Nt = 0; Nt < 8; ++Nt) {
            float v = agp[Nt]; v += __shfl_xor(v, 16); v += __shfl_xor(v, 32);
            aggr_x[(size_t)s * H_ + Nt * 16 + cl] = v;
            float g0 = gp0[Nt]; g0 += __shfl_xor(g0, 16); g0 += __shfl_xor(g0, 32); gp0[Nt] = g0;
            float g1 = gp1[Nt]; g1 += __shfl_xor(g1, 16); g1 += __shfl_xor(g1, 32); gp1[Nt] = g1;
            float g2 = gp2[Nt]; g2 += __shfl_xor(g2, 16); g2 += __shfl_xor(g2, 32); gp2[Nt] = g2;
        }
        float pr0 = 0.f, pr1 = 0.f, pr2 = 0.f;
#pragma unroll
        for (int Nt = 0; Nt < 8; ++Nt) {
            pr0 = fmaf(w2v0[Nt], gp0[Nt], pr0);
            pr1 = fmaf(w2v1[Nt], gp1[Nt], pr1);
            pr2 = fmaf(w2v2[Nt], gp2[Nt], pr2);
        }
#pragma unroll
        for (int off = 1; off < 16; off <<= 1) {
            pr0 += __shfl_xor(pr0, off);
            pr1 += __shfl_xor(pr1, off);
            pr2 += __shfl_xor(pr2, off);
        }
        f32x4 dsv = *(f32x4*)(wb + 4608 + (lane & 31) * 16);
        float q0 = dsv[0], q1 = dsv[1], q2 = dsv[2];
#pragma unroll
        for (int off = 1; off < 32; off <<= 1) {
            q0 += __shfl_xor(q0, off);
            q1 += __shfl_xor(q1, off);
            q2 += __shfl_xor(q2, off);
        }
        float cnt = cntv[s]; if (cnt < 1.f) cnt = 1.f;
        if (lane < 3) {
            float pr = lane == 0 ? pr0 : (lane == 1 ? pr1 : pr2);
            float qq = lane == 0 ? q0 : (lane == 1 ? q1 : q2);
            float bb = lane == 0 ? b20 : (lane == 1 ? b21 : b22);
            out_pos[s * 3 + lane] = pos_s[s * 3 + lane] + (pr + bb * qq) / cnt;
        }
    }
}

// ---------------- update GEMM: relu([x_d, aggr_x] @ W3 + b3) ----------------
__global__ __launch_bounds__(128) void out_kernel(
    const float* __restrict__ x, const float* __restrict__ W3,
    const float* __restrict__ b3, const int* __restrict__ idx_i,
    const float* __restrict__ aggr_x, float* __restrict__ out_x)
{
    __shared__ float rows[32][208];
    const int t = threadIdx.x;
    const int s0 = blockIdx.x * 32;
    const int sl = t >> 2, part = t & 3;
    const int s = s0 + sl;
    const int b = s >> 10;
    const int id = idx_i[s];
    {
        const float4* xr = (const float4*)(x + ((size_t)b * N_ + id) * D_);
        float4* rr = (float4*)&rows[sl][0];
#pragma unroll
        for (int q = 0; q < 4; ++q) rr[part * 4 + q] = xr[part * 4 + q];
        const float4* ar = (const float4*)(aggr_x + (size_t)s * H_);
        float4* rr2 = (float4*)&rows[sl][64];
#pragma unroll
        for (int q = 0; q < 8; ++q) rr2[part * 8 + q] = ar[part * 8 + q];
    }
    __syncthreads();
    float acc[32];
#pragma unroll
    for (int i = 0; i < 32; ++i) acc[i] = 0.f;
    for (int j4 = 0; j4 < 48; ++j4) {
        float w0 = W3[(j4 * 4 + 0) * H_ + t];
        float w1 = W3[(j4 * 4 + 1) * H_ + t];
        float w2 = W3[(j4 * 4 + 2) * H_ + t];
        float w3 = W3[(j4 * 4 + 3) * H_ + t];
#pragma unroll
        for (int i = 0; i < 32; ++i) {
            const float4 f = *(const float4*)&rows[i][j4 * 4];
            float a = acc[i];
            a = fmaf(f.x, w0, a); a = fmaf(f.y, w1, a);
            a = fmaf(f.z, w2, a); a = fmaf(f.w, w3, a);
            acc[i] = a;
        }
    }
    const float bb = b3[t];
#pragma unroll
    for (int i = 0; i < 32; ++i) {
        float v = acc[i] + bb;
        v = v > 0.f ? v : 0.f;
        out_x[(size_t)(s0 + i) * H_ + t] = v;
    }
}

extern "C" void kernel_launch(void* const* d_in, const int* in_sizes, int n_in,
                              void* d_out, int out_size, void* d_ws, size_t ws_size,
                              hipStream_t stream) {
    const float* x   = (const float*)d_in[0];
    const float* pos = (const float*)d_in[1];
    const float* W1  = (const float*)d_in[2];
    const float* b1  = (const float*)d_in[3];
    const float* W2  = (const float*)d_in[4];
    const float* b2  = (const float*)d_in[5];
    const float* W3  = (const float*)d_in[6];
    const float* b3  = (const float*)d_in[7];

    float* out_x   = (float*)d_out;                       // [16,1024,128]
    float* out_pos = (float*)d_out + 2097152;             // [16,1024,3]
    float* idx_f   = (float*)d_out + 2146304;             // [16,1024] as float

    char* ws = (char*)d_ws;
    int*      idx_i  = (int*)ws;                   // 16384 ints
    float*    pos_s  = (float*)(ws + 65536);       // 49152 floats
    int*      nbr    = (int*)(ws + 262144);        // 524288 ints
    float*    cntv   = (float*)(ws + 2359296);     // 16384 floats
    float*    aggr_x = (float*)(ws + 2424832);     // 2097152 floats
    ushort_t* x_bf16 = (ushort_t*)(ws + 10813440); // 16777216 ushorts (ends ~19.2MB)

    cvt_kernel<<<(B_ * N_ * D_) / (256 * 8), 256, 0, stream>>>(x, x_bf16);
    fps_kernel<<<B_, 256, 0, stream>>>(pos, idx_i, idx_f, pos_s);
    nbr_kernel<<<(B_ * NS_) / 4, 256, 0, stream>>>(pos, pos_s, nbr, cntv);
    msg_kernel<<<(B_ * NS_) / 16, 256, 0, stream>>>(x_bf16, pos, W1, b1, W2, b2,
                                                    pos_s, nbr, cntv, aggr_x, out_pos);
    out_kernel<<<(B_ * NS_) / 32, 128, 0, stream>>>(x, W3, b3, idx_i, aggr_x, out_x);
}

// Round 5
// 1063.924 us; speedup vs baseline: 1.1325x; 1.1178x over previous
//
#include <hip/hip_runtime.h>
#include <math.h>

#define B_ 16
#define N_ 4096
#define D_ 64
#define H_ 128
#define K_ 32
#define NS_ 1024
#define R2_ 0.04f
#define CAP_ 1024

typedef short short8 __attribute__((ext_vector_type(8)));
typedef float f32x4 __attribute__((ext_vector_type(4)));
typedef unsigned short ushort_t;

static __device__ __forceinline__ short f2bf(float f) {
    unsigned u = __float_as_uint(f);
    unsigned r = (u + 0x7FFFu + ((u >> 16) & 1u)) >> 16;   // round-to-nearest-even
    return (short)r;
}

template<int CTRL, int RM>
static __device__ __forceinline__ unsigned dppmov(unsigned v) {
    // old = v -> masked/invalid lanes keep v (identity for max/min)
    return (unsigned)__builtin_amdgcn_update_dpp((int)v, (int)v, CTRL, RM, 0xF, false);
}

#define DPP_FMAX_STEP(CTRL, RM)                                           \
    {                                                                     \
        float n = __uint_as_float(dppmov<CTRL, RM>(__float_as_uint(wm))); \
        wm = fmaxf(wm, n);                                                \
    }

#define DPP_UMIN_STEP(CTRL, RM)                                           \
    {                                                                     \
        unsigned n = dppmov<CTRL, RM>(cand);                              \
        cand = n < cand ? n : cand;                                       \
    }

#define DPP_UMIN_STEP_V(var, CTRL, RM)                                    \
    {                                                                     \
        unsigned n = dppmov<CTRL, RM>(var);                               \
        var = n < var ? n : var;                                          \
    }

// ---------------- x -> bf16 pre-convert (RNE, identical to f2bf) ----------
__global__ __launch_bounds__(256) void cvt_kernel(
    const float* __restrict__ x, ushort_t* __restrict__ xb)
{
    const size_t i = ((size_t)blockIdx.x * 256 + threadIdx.x) * 8;
    float4 a = *(const float4*)(x + i);
    float4 c = *(const float4*)(x + i + 4);
    short8 o;
    o[0] = f2bf(a.x); o[1] = f2bf(a.y); o[2] = f2bf(a.z); o[3] = f2bf(a.w);
    o[4] = f2bf(c.x); o[5] = f2bf(c.y); o[6] = f2bf(c.z); o[7] = f2bf(c.w);
    *(short8*)(xb + i) = o;
}

// ---------------- FPS v13: v8 verbatim + register-tree cross-wave reduce ---
// v8 (647us, best measured) kept byte-identical through the barrier. Only
// the post-barrier tournament changes: the 4 wave candidates (u64 key +
// coords) are read via uniform-address broadcast LDS loads (latencies
// overlap in one window) and reduced with a 3-node u64-compare register
// tree (v_cmp_lt_u64 + cndmask). This removes both DPP SLOT_STEPs (with
// their hazard nops), the readfirstlane, and the 3 readlane SALU
// round-trips from the per-iteration critical path. Keys are unique across
// waves (disjoint point sets, ~widx in the low word), so the max-tree is
// exact; selection semantics are bit-identical to v8.
__global__ __launch_bounds__(256, 1) void fps_kernel(
    const float* __restrict__ pos, int* __restrict__ idx_i,
    float* __restrict__ idx_f, float* __restrict__ pos_s)
{
    __shared__ float4 lpos4[N_];                         // 64 KB
    __shared__ float4 sres[NS_];                         // 16 KB
    __shared__ __align__(16) unsigned long long skey[2][4];
    __shared__ float4 scoord[2][4];
    const int b = blockIdx.x;
    const int t = threadIdx.x;
    const int wv = t >> 6;
    const int lane = t & 63;
    const float* posb = pos + (size_t)b * N_ * 3;
    for (int p = t; p < N_; p += 256)
        lpos4[p] = make_float4(posb[3 * p + 0], posb[3 * p + 1], posb[3 * p + 2], 0.f);
    __syncthreads();

    float px[16], py[16], pz[16], dist[16];
#pragma unroll
    for (int j = 0; j < 16; ++j) {
        float4 v = lpos4[t + 256 * j];
        px[j] = v.x; py[j] = v.y; pz[j] = v.z;
        dist[j] = 1e10f;
    }
    unsigned curidx = 0;
    float4 c0 = lpos4[0];
    float ccx = c0.x, ccy = c0.y, ccz = c0.z;

    for (int ns = 0; ns < NS_; ++ns) {
        if (t == 0)
            sres[ns] = make_float4(ccx, ccy, ccz, __uint_as_float(curidx));
        // ---- update dists + per-lane argmax (bit-exact d2 chain) ----
        float bv = -1.f; int bj = 0;
#pragma unroll
        for (int j = 0; j < 16; ++j) {
            float dx = __fsub_rn(px[j], ccx);
            float dy = __fsub_rn(py[j], ccy);
            float dz = __fsub_rn(pz[j], ccz);
            float d2 = __fadd_rn(__fadd_rn(__fmul_rn(dx, dx), __fmul_rn(dy, dy)), __fmul_rn(dz, dz));
            float dn = fminf(dist[j], d2);
            dist[j] = dn;
            bool g = dn > bv;                 // strict > + ascending j => lowest idx on tie
            bv = g ? dn : bv;
            bj = g ? j : bj;
        }
        // ---- wave fp32 max via DPP (result valid in lane 63) ----
        float wm = bv;
        DPP_FMAX_STEP(0x111, 0xF)   // row_shr:1
        DPP_FMAX_STEP(0x112, 0xF)   // row_shr:2
        DPP_FMAX_STEP(0x114, 0xF)   // row_shr:4
        DPP_FMAX_STEP(0x118, 0xF)   // row_shr:8
        DPP_FMAX_STEP(0x142, 0xA)   // row_bcast:15
        DPP_FMAX_STEP(0x143, 0xC)   // row_bcast:31
        const float wavemax = __uint_as_float(
            (unsigned)__builtin_amdgcn_readlane((int)__float_as_uint(wm), 63));
        // ---- min global idx among max-achieving lanes ----
        const unsigned pidx = (unsigned)t + ((unsigned)bj << 8);   // == global point idx
        const unsigned long long mask = __ballot(bv == wavemax);
        unsigned widx;
        if (__popcll(mask) == 1) {             // unique winner (common case)
            const int wl = __ffsll((long long)mask) - 1;
            widx = (unsigned)__builtin_amdgcn_readlane((int)pidx, wl);
        } else {                                // exact tie fallback
            unsigned cand = (bv == wavemax) ? pidx : 0xFFFFFFFFu;
            DPP_UMIN_STEP(0x111, 0xF)
            DPP_UMIN_STEP(0x112, 0xF)
            DPP_UMIN_STEP(0x114, 0xF)
            DPP_UMIN_STEP(0x118, 0xF)
            DPP_UMIN_STEP(0x142, 0xA)
            DPP_UMIN_STEP(0x143, 0xC)
            widx = (unsigned)__builtin_amdgcn_readlane((int)cand, 63);
        }
        // prefetch this wave's winner coords (broadcast, uniform addr) so the
        // coord fetch latency hides under the key store + barrier wait
        float4 wc = lpos4[widx];
        if (lane == 0) {
            skey[ns & 1][wv] = (((unsigned long long)__float_as_uint(wavemax)) << 32)
                             | (unsigned long long)(0xFFFFFFFFu - widx);
            scoord[ns & 1][wv] = wc;
        }
        __syncthreads();
        // ---- cross-wave reduce: uniform broadcast LDS reads + 3-node u64
        //      compare tree in registers (no DPP hazards, no SALU trips) ----
        {
            const unsigned long long k0 = skey[ns & 1][0];
            const unsigned long long k1 = skey[ns & 1][1];
            const unsigned long long k2 = skey[ns & 1][2];
            const unsigned long long k3 = skey[ns & 1][3];
            const float4 s0 = scoord[ns & 1][0];
            const float4 s1 = scoord[ns & 1][1];
            const float4 s2 = scoord[ns & 1][2];
            const float4 s3 = scoord[ns & 1][3];
            const bool a = k1 > k0;
            const unsigned long long ka = a ? k1 : k0;
            const float ax = a ? s1.x : s0.x;
            const float ay = a ? s1.y : s0.y;
            const float az = a ? s1.z : s0.z;
            const bool c = k3 > k2;
            const unsigned long long kc = c ? k3 : k2;
            const float cx = c ? s3.x : s2.x;
            const float cy = c ? s3.y : s2.y;
            const float cz = c ? s3.z : s2.z;
            const bool f = kc > ka;
            const unsigned long long kb = f ? kc : ka;
            ccx = f ? cx : ax;
            ccy = f ? cy : ay;
            ccz = f ? cz : az;
            curidx = 0xFFFFFFFFu - (unsigned)(kb & 0xFFFFFFFFull);
        }
    }
    __syncthreads();
    for (int i = t; i < NS_; i += 256) {
        float4 r = sres[i];
        unsigned id = __float_as_uint(r.w);
        idx_i[b * NS_ + i] = (int)id;
        idx_f[b * NS_ + i] = (float)id;
        pos_s[(b * NS_ + i) * 3 + 0] = r.x;
        pos_s[(b * NS_ + i) * 3 + 1] = r.y;
        pos_s[(b * NS_ + i) * 3 + 2] = r.z;
    }
}

// ---------------- radius-KNN v5: split-phase (d2-min DPP + ballot) --------
__global__ __launch_bounds__(256) void nbr_kernel(
    const float* __restrict__ pos, const float* __restrict__ pos_s,
    int* __restrict__ nbr, float* __restrict__ cntv)
{
    __shared__ unsigned long long ck[4][CAP_];
    const int w = threadIdx.x >> 6;
    const int lane = threadIdx.x & 63;
    const int s = blockIdx.x * 4 + w;
    const int b = s >> 10;
    const float cx = pos_s[s * 3 + 0], cy = pos_s[s * 3 + 1], cz = pos_s[s * 3 + 2];
    const float* posb = pos + (size_t)b * N_ * 3;
    int m = 0;
    for (int base = 0; base < N_; base += 64) {
        int p = base + lane;
        float dx = __fsub_rn(posb[3 * p + 0], cx);
        float dy = __fsub_rn(posb[3 * p + 1], cy);
        float dz = __fsub_rn(posb[3 * p + 2], cz);
        float d2 = __fadd_rn(__fadd_rn(__fmul_rn(dx, dx), __fmul_rn(dy, dy)), __fmul_rn(dz, dz));
        bool in = (d2 <= R2_);
        unsigned long long msk = __ballot(in);
        int before = __popcll(msk & ((1ull << lane) - 1ull));
        int slot = m + before;
        if (in && slot < CAP_)
            ck[w][slot] = ((unsigned long long)__float_as_uint(d2) << 32) | (unsigned)p;
        m += __popcll(msk);
    }
    if (m > CAP_) m = CAP_;
    __asm__ volatile("s_waitcnt lgkmcnt(0)" ::: "memory");
    int kcnt = m < K_ ? m : K_;
    if (m <= 256) {
        // register-resident candidates; selection = u64 local scan +
        // u32 d2-min DPP + ballot winner (exact idx-umin fallback on ties)
        unsigned long long kr[4];
#pragma unroll
        for (int r = 0; r < 4; ++r) {
            int q = r * 64 + lane;
            unsigned long long v = ck[w][q & (CAP_ - 1)];
            kr[r] = (q < m) ? v : ~0ull;
        }
        unsigned chosen = 0;
        for (int k = 0; k < kcnt; ++k) {
            unsigned long long localk = ~0ull; int br = -1;
#pragma unroll
            for (int r = 0; r < 4; ++r) {
                bool ok = (!((chosen >> r) & 1u)) && (kr[r] < localk);
                localk = ok ? kr[r] : localk;
                br = ok ? r : br;
            }
            const unsigned mybits = (unsigned)(localk >> 32);
            const unsigned myidx = (unsigned)localk;
            unsigned wb = mybits;
            DPP_UMIN_STEP_V(wb, 0x111, 0xF)
            DPP_UMIN_STEP_V(wb, 0x112, 0xF)
            DPP_UMIN_STEP_V(wb, 0x114, 0xF)
            DPP_UMIN_STEP_V(wb, 0x118, 0xF)
            DPP_UMIN_STEP_V(wb, 0x142, 0xA)
            DPP_UMIN_STEP_V(wb, 0x143, 0xC)
            const unsigned minbits = (unsigned)__builtin_amdgcn_readlane((int)wb, 63);
            const unsigned long long wmask = __ballot(mybits == minbits);
            unsigned widx;
            if (__popcll(wmask) == 1) {
                const int wl = __ffsll((long long)wmask) - 1;
                widx = (unsigned)__builtin_amdgcn_readlane((int)myidx, wl);
            } else {
                unsigned cand = (mybits == minbits) ? myidx : 0xFFFFFFFFu;
                DPP_UMIN_STEP(0x111, 0xF)
                DPP_UMIN_STEP(0x112, 0xF)
                DPP_UMIN_STEP(0x114, 0xF)
                DPP_UMIN_STEP(0x118, 0xF)
                DPP_UMIN_STEP(0x142, 0xA)
                DPP_UMIN_STEP(0x143, 0xC)
                widx = (unsigned)__builtin_amdgcn_readlane((int)cand, 63);
            }
            if (mybits == minbits && myidx == widx) chosen |= 1u << br;
            if (lane == 0) nbr[s * K_ + k] = (int)widx;
        }
    } else {
        // exact fallback (rare): LDS-scan selection with u64 DPP min
        unsigned chosen = 0;
        for (int k = 0; k < kcnt; ++k) {
            unsigned long long localk = ~0ull; int bslot = -1;
            for (int r = 0; r * 64 + lane < m; ++r) {
                if (chosen & (1u << r)) continue;
                int q = r * 64 + lane;
                unsigned long long key = ck[w][q];
                if (key < localk) { localk = key; bslot = q; }
            }
            unsigned kh = (unsigned)(localk >> 32), kl = (unsigned)localk;
#define DPP_MIN_STEP2(CTRL, RM)                                           \
            {                                                             \
                unsigned nh = dppmov<CTRL, RM>(kh);                       \
                unsigned nl = dppmov<CTRL, RM>(kl);                       \
                unsigned long long nk = (((unsigned long long)nh) << 32) | nl; \
                unsigned long long ok = (((unsigned long long)kh) << 32) | kl; \
                if (nk < ok) { kh = nh; kl = nl; }                        \
            }
            DPP_MIN_STEP2(0x111, 0xF)
            DPP_MIN_STEP2(0x112, 0xF)
            DPP_MIN_STEP2(0x114, 0xF)
            DPP_MIN_STEP2(0x118, 0xF)
            DPP_MIN_STEP2(0x142, 0xA)
            DPP_MIN_STEP2(0x143, 0xC)
#undef DPP_MIN_STEP2
            unsigned mh = (unsigned)__builtin_amdgcn_readlane((int)kh, 63);
            unsigned ml = (unsigned)__builtin_amdgcn_readlane((int)kl, 63);
            unsigned long long bk = (((unsigned long long)mh) << 32) | ml;
            if (localk == bk && bslot >= 0) chosen |= 1u << (bslot >> 6);
            if (lane == 0) nbr[s * K_ + k] = (int)(bk & 0xFFFFFFFFull);
        }
    }
    if (lane == 0) {
        for (int k = kcnt; k < K_; ++k) nbr[s * K_ + k] = -1;
        cntv[s] = (float)kcnt;
    }
}

// ---------------- message MLP v5: bf16 MFMA, pre-converted x ----------------
__global__ __launch_bounds__(256) void msg_kernel(
    const ushort_t* __restrict__ xb, const float* __restrict__ pos,
    const float* __restrict__ W1, const float* __restrict__ b1,
    const float* __restrict__ W2, const float* __restrict__ b2,
    const float* __restrict__ pos_s, const int* __restrict__ nbr,
    const float* __restrict__ cntv, float* __restrict__ aggr_x,
    float* __restrict__ out_pos)
{
    __shared__ __align__(16) char smem[4 * 5120];
    const int t = threadIdx.x;
    const int wv = t >> 6, lane = t & 63;
    const int quad = lane >> 4, cl = lane & 15;
    char* wb = smem + wv * 5120;

    short8 bfrag[8][2];
    float b1v[8], w1dv[8], w2v0[8], w2v1[8], w2v2[8];
#pragma unroll
    for (int Nt = 0; Nt < 8; ++Nt) {
        const int h = Nt * 16 + cl;
#pragma unroll
        for (int ks = 0; ks < 2; ++ks) {
            short8 f;
#pragma unroll
            for (int jj = 0; jj < 8; ++jj)
                f[jj] = f2bf(W1[(ks * 32 + quad * 8 + jj) * H_ + h]);
            bfrag[Nt][ks] = f;
        }
        b1v[Nt] = b1[h];
        w1dv[Nt] = W1[64 * H_ + h];
        w2v0[Nt] = W2[h * 3 + 0];
        w2v1[Nt] = W2[h * 3 + 1];
        w2v2[Nt] = W2[h * 3 + 2];
    }
    const float b20 = b2[0], b21 = b2[1], b22 = b2[2];

    const int kkg = lane >> 1, half = lane & 1;
    for (int i = 0; i < 4; ++i) {
        const int s = blockIdx.x * 16 + wv * 4 + i;
        const int b = s >> 10;
        const int n = nbr[s * K_ + kkg];
        {
            char* frow = wb + kkg * 144 + half * 64;
            if (n >= 0) {
                const short8* xr = (const short8*)(xb + ((size_t)b * N_ + n) * D_) + half * 4;
#pragma unroll
                for (int q = 0; q < 4; ++q) *(short8*)(frow + q * 16) = xr[q];
            } else {
                short8 z = {0, 0, 0, 0, 0, 0, 0, 0};
#pragma unroll
                for (int q = 0; q < 4; ++q) *(short8*)(frow + q * 16) = z;
            }
            if (half == 0) {
                float dxm = 0.f, dym = 0.f, dzm = 0.f, de = -1.f;
                if (n >= 0) {
                    const float* pj = pos + ((size_t)b * N_ + n) * 3;
                    float dx = pj[0] - pos_s[s * 3 + 0];
                    float dy = pj[1] - pos_s[s * 3 + 1];
                    float dz = pj[2] - pos_s[s * 3 + 2];
                    float d2 = dx * dx + dy * dy + dz * dz;
                    de = d2 > 0.f ? sqrtf(d2) : 0.f;
                    dxm = dx; dym = dy; dzm = dz;
                }
                f32x4 sv = {dxm, dym, dzm, de};
                *(f32x4*)(wb + 4608 + kkg * 16) = sv;
            }
        }
        float agp[8] = {0, 0, 0, 0, 0, 0, 0, 0};
        float gp0[8] = {0, 0, 0, 0, 0, 0, 0, 0};
        float gp1[8] = {0, 0, 0, 0, 0, 0, 0, 0};
        float gp2[8] = {0, 0, 0, 0, 0, 0, 0, 0};
#pragma unroll
        for (int Mt = 0; Mt < 2; ++Mt) {
            short8 a0 = *(short8*)(wb + (Mt * 16 + cl) * 144 + quad * 16);
            short8 a1 = *(short8*)(wb + (Mt * 16 + cl) * 144 + 64 + quad * 16);
            f32x4 acc[8];
#pragma unroll
            for (int Nt = 0; Nt < 8; ++Nt) {
                f32x4 z = {0.f, 0.f, 0.f, 0.f};
                z = __builtin_amdgcn_mfma_f32_16x16x32_bf16(a0, bfrag[Nt][0], z, 0, 0, 0);
                z = __builtin_amdgcn_mfma_f32_16x16x32_bf16(a1, bfrag[Nt][1], z, 0, 0, 0);
                acc[Nt] = z;
            }
            f32x4 sd[4];
#pragma unroll
            for (int r = 0; r < 4; ++r)
                sd[r] = *(f32x4*)(wb + 4608 + (Mt * 16 + quad * 4 + r) * 16);
#pragma unroll
            for (int Nt = 0; Nt < 8; ++Nt) {
#pragma unroll
                for (int r = 0; r < 4; ++r) {
                    float dr = sd[r][3];
                    float wgt = dr >= 0.f ? 1.f : 0.f;
                    float dd = dr >= 0.f ? dr : 0.f;
                    float e = fmaf(dd, w1dv[Nt], acc[Nt][r]) + b1v[Nt];
                    e = e > 0.f ? e : 0.f;
                    agp[Nt] = fmaf(wgt, e, agp[Nt]);
                    gp0[Nt] = fmaf(sd[r][0], e, gp0[Nt]);
                    gp1[Nt] = fmaf(sd[r][1], e, gp1[Nt]);
                    gp2[Nt] = fmaf(sd[r][2], e, gp2[Nt]);
                }
            }
        }
#pragma unroll
        for (int Nt = 0; Nt < 8; ++Nt) {
            float v = agp[Nt]; v += __shfl_xor(v, 16); v += __shfl_xor(v, 32);
            aggr_x[(size_t)s * H_ + Nt * 16 + cl] = v;
            float g0 = gp0[Nt]; g0 += __shfl_xor(g0, 16); g0 += __shfl_xor(g0, 32); gp0[Nt] = g0;
            float g1 = gp1[Nt]; g1 += __shfl_xor(g1, 16); g1 += __shfl_xor(g1, 32); gp1[Nt] = g1;
            float g2 = gp2[Nt]; g2 += __shfl_xor(g2, 16); g2 += __shfl_xor(g2, 32); gp2[Nt] = g2;
        }
        float pr0 = 0.f, pr1 = 0.f, pr2 = 0.f;
#pragma unroll
        for (int Nt = 0; Nt < 8; ++Nt) {
            pr0 = fmaf(w2v0[Nt], gp0[Nt], pr0);
            pr1 = fmaf(w2v1[Nt], gp1[Nt], pr1);
            pr2 = fmaf(w2v2[Nt], gp2[Nt], pr2);
        }
#pragma unroll
        for (int off = 1; off < 16; off <<= 1) {
            pr0 += __shfl_xor(pr0, off);
            pr1 += __shfl_xor(pr1, off);
            pr2 += __shfl_xor(pr2, off);
        }
        f32x4 dsv = *(f32x4*)(wb + 4608 + (lane & 31) * 16);
        float q0 = dsv[0], q1 = dsv[1], q2 = dsv[2];
#pragma unroll
        for (int off = 1; off < 32; off <<= 1) {
            q0 += __shfl_xor(q0, off);
            q1 += __shfl_xor(q1, off);
            q2 += __shfl_xor(q2, off);
        }
        float cnt = cntv[s]; if (cnt < 1.f) cnt = 1.f;
        if (lane < 3) {
            float pr = lane == 0 ? pr0 : (lane == 1 ? pr1 : pr2);
            float qq = lane == 0 ? q0 : (lane == 1 ? q1 : q2);
            float bb = lane == 0 ? b20 : (lane == 1 ? b21 : b22);
            out_pos[s * 3 + lane] = pos_s[s * 3 + lane] + (pr + bb * qq) / cnt;
        }
    }
}

// ---------------- update GEMM: relu([x_d, aggr_x] @ W3 + b3) ----------------
__global__ __launch_bounds__(128) void out_kernel(
    const float* __restrict__ x, const float* __restrict__ W3,
    const float* __restrict__ b3, const int* __restrict__ idx_i,
    const float* __restrict__ aggr_x, float* __restrict__ out_x)
{
    __shared__ float rows[32][208];
    const int t = threadIdx.x;
    const int s0 = blockIdx.x * 32;
    const int sl = t >> 2, part = t & 3;
    const int s = s0 + sl;
    const int b = s >> 10;
    const int id = idx_i[s];
    {
        const float4* xr = (const float4*)(x + ((size_t)b * N_ + id) * D_);
        float4* rr = (float4*)&rows[sl][0];
#pragma unroll
        for (int q = 0; q < 4; ++q) rr[part * 4 + q] = xr[part * 4 + q];
        const float4* ar = (const float4*)(aggr_x + (size_t)s * H_);
        float4* rr2 = (float4*)&rows[sl][64];
#pragma unroll
        for (int q = 0; q < 8; ++q) rr2[part * 8 + q] = ar[part * 8 + q];
    }
    __syncthreads();
    float acc[32];
#pragma unroll
    for (int i = 0; i < 32; ++i) acc[i] = 0.f;
    for (int j4 = 0; j4 < 48; ++j4) {
        float w0 = W3[(j4 * 4 + 0) * H_ + t];
        float w1 = W3[(j4 * 4 + 1) * H_ + t];
        float w2 = W3[(j4 * 4 + 2) * H_ + t];
        float w3 = W3[(j4 * 4 + 3) * H_ + t];
#pragma unroll
        for (int i = 0; i < 32; ++i) {
            const float4 f = *(const float4*)&rows[i][j4 * 4];
            float a = acc[i];
            a = fmaf(f.x, w0, a); a = fmaf(f.y, w1, a);
            a = fmaf(f.z, w2, a); a = fmaf(f.w, w3, a);
            acc[i] = a;
        }
    }
    const float bb = b3[t];
#pragma unroll
    for (int i = 0; i < 32; ++i) {
        float v = acc[i] + bb;
        v = v > 0.f ? v : 0.f;
        out_x[(size_t)(s0 + i) * H_ + t] = v;
    }
}

extern "C" void kernel_launch(void* const* d_in, const int* in_sizes, int n_in,
                              void* d_out, int out_size, void* d_ws, size_t ws_size,
                              hipStream_t stream) {
    const float* x   = (const float*)d_in[0];
    const float* pos = (const float*)d_in[1];
    const float* W1  = (const float*)d_in[2];
    const float* b1  = (const float*)d_in[3];
    const float* W2  = (const float*)d_in[4];
    const float* b2  = (const float*)d_in[5];
    const float* W3  = (const float*)d_in[6];
    const float* b3  = (const float*)d_in[7];

    float* out_x   = (float*)d_out;                       // [16,1024,128]
    float* out_pos = (float*)d_out + 2097152;             // [16,1024,3]
    float* idx_f   = (float*)d_out + 2146304;             // [16,1024] as float

    char* ws = (char*)d_ws;
    int*      idx_i  = (int*)ws;                   // 16384 ints
    float*    pos_s  = (float*)(ws + 65536);       // 49152 floats
    int*      nbr    = (int*)(ws + 262144);        // 524288 ints
    float*    cntv   = (float*)(ws + 2359296);     // 16384 floats
    float*    aggr_x = (float*)(ws + 2424832);     // 2097152 floats
    ushort_t* x_bf16 = (ushort_t*)(ws + 10813440); // 16777216 ushorts (ends ~19.2MB)

    cvt_kernel<<<(B_ * N_ * D_) / (256 * 8), 256, 0, stream>>>(x, x_bf16);
    fps_kernel<<<B_, 256, 0, stream>>>(pos, idx_i, idx_f, pos_s);
    nbr_kernel<<<(B_ * NS_) / 4, 256, 0, stream>>>(pos, pos_s, nbr, cntv);
    msg_kernel<<<(B_ * NS_) / 16, 256, 0, stream>>>(x_bf16, pos, W1, b1, W2, b2,
                                                    pos_s, nbr, cntv, aggr_x, out_pos);
    out_kernel<<<(B_ * NS_) / 32, 128, 0, stream>>>(x, W3, b3, idx_i, aggr_x, out_x);
}

// Round 6
// 983.698 us; speedup vs baseline: 1.2248x; 1.0816x over previous
//
#include <hip/hip_runtime.h>
#include <math.h>

#define B_ 16
#define N_ 4096
#define D_ 64
#define H_ 128
#define K_ 32
#define NS_ 1024
#define R2_ 0.04f
#define CAP_ 1024

typedef short short8 __attribute__((ext_vector_type(8)));
typedef float f32x4 __attribute__((ext_vector_type(4)));
typedef unsigned short ushort_t;

static __device__ __forceinline__ short f2bf(float f) {
    unsigned u = __float_as_uint(f);
    unsigned r = (u + 0x7FFFu + ((u >> 16) & 1u)) >> 16;   // round-to-nearest-even
    return (short)r;
}

template<int CTRL, int RM>
static __device__ __forceinline__ unsigned dppmov(unsigned v) {
    // old = v -> masked/invalid lanes keep v (identity for max/min)
    return (unsigned)__builtin_amdgcn_update_dpp((int)v, (int)v, CTRL, RM, 0xF, false);
}

#define DPP_FMAX_STEP(CTRL, RM)                                           \
    {                                                                     \
        float n = __uint_as_float(dppmov<CTRL, RM>(__float_as_uint(wm))); \
        wm = fmaxf(wm, n);                                                \
    }

#define DPP_UMIN_STEP(CTRL, RM)                                           \
    {                                                                     \
        unsigned n = dppmov<CTRL, RM>(cand);                              \
        cand = n < cand ? n : cand;                                       \
    }

#define DPP_UMIN_STEP_V(var, CTRL, RM)                                    \
    {                                                                     \
        unsigned n = dppmov<CTRL, RM>(var);                               \
        var = n < var ? n : var;                                          \
    }

// ---------------- FPS v14: v8 VERBATIM + cvt fused as extra blocks --------
// fps iteration body/tail byte-identical to v8 (647us, best of 6 measured
// variants; every structural change regressed). New: blocks >= 16 of the
// same launch perform the x->bf16 pre-convert (formerly cvt_kernel) on the
// 240 CUs fps doesn't use -- fully hidden under fps's 647us. cvt blocks
// can never share a CU with an fps block (2 x 82KB LDS > 160KB), so the
// latency-critical fps schedule is untouched by construction.
__global__ __launch_bounds__(256, 1) void fps_kernel(
    const float* __restrict__ pos, int* __restrict__ idx_i,
    float* __restrict__ idx_f, float* __restrict__ pos_s,
    const float* __restrict__ x, ushort_t* __restrict__ xb)
{
    __shared__ float4 lpos4[N_];                         // 64 KB
    __shared__ float4 sres[NS_];                         // 16 KB
    __shared__ unsigned long long skey[2][4];
    __shared__ float4 scoord[2][4];
    if (blockIdx.x >= B_) {
        // ---- fused cvt branch (block-uniform; no barriers executed) ----
        const size_t i = ((size_t)(blockIdx.x - B_) * 256 + threadIdx.x) * 8;
        float4 a = *(const float4*)(x + i);
        float4 c = *(const float4*)(x + i + 4);
        short8 o;
        o[0] = f2bf(a.x); o[1] = f2bf(a.y); o[2] = f2bf(a.z); o[3] = f2bf(a.w);
        o[4] = f2bf(c.x); o[5] = f2bf(c.y); o[6] = f2bf(c.z); o[7] = f2bf(c.w);
        *(short8*)(xb + i) = o;
        return;
    }
    const int b = blockIdx.x;
    const int t = threadIdx.x;
    const int wv = t >> 6;
    const int lane = t & 63;
    const float* posb = pos + (size_t)b * N_ * 3;
    for (int p = t; p < N_; p += 256)
        lpos4[p] = make_float4(posb[3 * p + 0], posb[3 * p + 1], posb[3 * p + 2], 0.f);
    __syncthreads();

    float px[16], py[16], pz[16], dist[16];
#pragma unroll
    for (int j = 0; j < 16; ++j) {
        float4 v = lpos4[t + 256 * j];
        px[j] = v.x; py[j] = v.y; pz[j] = v.z;
        dist[j] = 1e10f;
    }
    unsigned curidx = 0;
    float4 c0 = lpos4[0];
    float ccx = c0.x, ccy = c0.y, ccz = c0.z;

    for (int ns = 0; ns < NS_; ++ns) {
        if (t == 0)
            sres[ns] = make_float4(ccx, ccy, ccz, __uint_as_float(curidx));
        // ---- update dists + per-lane argmax (bit-exact d2 chain) ----
        float bv = -1.f; int bj = 0;
#pragma unroll
        for (int j = 0; j < 16; ++j) {
            float dx = __fsub_rn(px[j], ccx);
            float dy = __fsub_rn(py[j], ccy);
            float dz = __fsub_rn(pz[j], ccz);
            float d2 = __fadd_rn(__fadd_rn(__fmul_rn(dx, dx), __fmul_rn(dy, dy)), __fmul_rn(dz, dz));
            float dn = fminf(dist[j], d2);
            dist[j] = dn;
            bool g = dn > bv;                 // strict > + ascending j => lowest idx on tie
            bv = g ? dn : bv;
            bj = g ? j : bj;
        }
        // ---- wave fp32 max via DPP (result valid in lane 63) ----
        float wm = bv;
        DPP_FMAX_STEP(0x111, 0xF)   // row_shr:1
        DPP_FMAX_STEP(0x112, 0xF)   // row_shr:2
        DPP_FMAX_STEP(0x114, 0xF)   // row_shr:4
        DPP_FMAX_STEP(0x118, 0xF)   // row_shr:8
        DPP_FMAX_STEP(0x142, 0xA)   // row_bcast:15
        DPP_FMAX_STEP(0x143, 0xC)   // row_bcast:31
        const float wavemax = __uint_as_float(
            (unsigned)__builtin_amdgcn_readlane((int)__float_as_uint(wm), 63));
        // ---- min global idx among max-achieving lanes ----
        const unsigned pidx = (unsigned)t + ((unsigned)bj << 8);   // == global point idx
        const unsigned long long mask = __ballot(bv == wavemax);
        unsigned widx;
        if (__popcll(mask) == 1) {             // unique winner (common case)
            const int wl = __ffsll((long long)mask) - 1;
            widx = (unsigned)__builtin_amdgcn_readlane((int)pidx, wl);
        } else {                                // exact tie fallback
            unsigned cand = (bv == wavemax) ? pidx : 0xFFFFFFFFu;
            DPP_UMIN_STEP(0x111, 0xF)
            DPP_UMIN_STEP(0x112, 0xF)
            DPP_UMIN_STEP(0x114, 0xF)
            DPP_UMIN_STEP(0x118, 0xF)
            DPP_UMIN_STEP(0x142, 0xA)
            DPP_UMIN_STEP(0x143, 0xC)
            widx = (unsigned)__builtin_amdgcn_readlane((int)cand, 63);
        }
        // prefetch this wave's winner coords (broadcast, uniform addr) so the
        // coord fetch latency hides under the key store + barrier wait
        float4 wc = lpos4[widx];
        if (lane == 0) {
            skey[ns & 1][wv] = (((unsigned long long)__float_as_uint(wavemax)) << 32)
                             | (unsigned long long)(0xFFFFFFFFu - widx);
            scoord[ns & 1][wv] = wc;
        }
        __syncthreads();
        // ---- 4-slot u64-max tournament (carrying slot id); coords via
        //      v_readlane from the slot-holder lane (no second LDS read) ----
        {
            unsigned sid = (unsigned)(lane & 3);
            unsigned long long skv = skey[ns & 1][sid];
            float4 scv = scoord[ns & 1][sid];
            unsigned kh2 = (unsigned)(skv >> 32), kl2 = (unsigned)skv;
#define SLOT_STEP(CTRL)                                                        \
            {                                                                  \
                unsigned nh = dppmov<CTRL, 0xF>(kh2);                          \
                unsigned nl = dppmov<CTRL, 0xF>(kl2);                          \
                unsigned nsid = dppmov<CTRL, 0xF>(sid);                        \
                unsigned long long nk = (((unsigned long long)nh) << 32) | nl; \
                unsigned long long ok = (((unsigned long long)kh2) << 32) | kl2;\
                if (nk > ok) { kh2 = nh; kl2 = nl; sid = nsid; }               \
            }
            SLOT_STEP(0x101)   // row_shl:1
            SLOT_STEP(0x102)   // row_shl:2
#undef SLOT_STEP
            const int slotwin = __builtin_amdgcn_readfirstlane((int)sid);
            curidx = 0xFFFFFFFFu - (unsigned)__builtin_amdgcn_readfirstlane((int)kl2);
            ccx = __uint_as_float((unsigned)__builtin_amdgcn_readlane(
                      (int)__float_as_uint(scv.x), slotwin));
            ccy = __uint_as_float((unsigned)__builtin_amdgcn_readlane(
                      (int)__float_as_uint(scv.y), slotwin));
            ccz = __uint_as_float((unsigned)__builtin_amdgcn_readlane(
                      (int)__float_as_uint(scv.z), slotwin));
        }
    }
    __syncthreads();
    for (int i = t; i < NS_; i += 256) {
        float4 r = sres[i];
        unsigned id = __float_as_uint(r.w);
        idx_i[b * NS_ + i] = (int)id;
        idx_f[b * NS_ + i] = (float)id;
        pos_s[(b * NS_ + i) * 3 + 0] = r.x;
        pos_s[(b * NS_ + i) * 3 + 1] = r.y;
        pos_s[(b * NS_ + i) * 3 + 2] = r.z;
    }
}

// ---------------- radius-KNN v5: split-phase (d2-min DPP + ballot) --------
__global__ __launch_bounds__(256) void nbr_kernel(
    const float* __restrict__ pos, const float* __restrict__ pos_s,
    int* __restrict__ nbr, float* __restrict__ cntv)
{
    __shared__ unsigned long long ck[4][CAP_];
    const int w = threadIdx.x >> 6;
    const int lane = threadIdx.x & 63;
    const int s = blockIdx.x * 4 + w;
    const int b = s >> 10;
    const float cx = pos_s[s * 3 + 0], cy = pos_s[s * 3 + 1], cz = pos_s[s * 3 + 2];
    const float* posb = pos + (size_t)b * N_ * 3;
    int m = 0;
    for (int base = 0; base < N_; base += 64) {
        int p = base + lane;
        float dx = __fsub_rn(posb[3 * p + 0], cx);
        float dy = __fsub_rn(posb[3 * p + 1], cy);
        float dz = __fsub_rn(posb[3 * p + 2], cz);
        float d2 = __fadd_rn(__fadd_rn(__fmul_rn(dx, dx), __fmul_rn(dy, dy)), __fmul_rn(dz, dz));
        bool in = (d2 <= R2_);
        unsigned long long msk = __ballot(in);
        int before = __popcll(msk & ((1ull << lane) - 1ull));
        int slot = m + before;
        if (in && slot < CAP_)
            ck[w][slot] = ((unsigned long long)__float_as_uint(d2) << 32) | (unsigned)p;
        m += __popcll(msk);
    }
    if (m > CAP_) m = CAP_;
    __asm__ volatile("s_waitcnt lgkmcnt(0)" ::: "memory");
    int kcnt = m < K_ ? m : K_;
    if (m <= 256) {
        // register-resident candidates; selection = u64 local scan +
        // u32 d2-min DPP + ballot winner (exact idx-umin fallback on ties)
        unsigned long long kr[4];
#pragma unroll
        for (int r = 0; r < 4; ++r) {
            int q = r * 64 + lane;
            unsigned long long v = ck[w][q & (CAP_ - 1)];
            kr[r] = (q < m) ? v : ~0ull;
        }
        unsigned chosen = 0;
        for (int k = 0; k < kcnt; ++k) {
            unsigned long long localk = ~0ull; int br = -1;
#pragma unroll
            for (int r = 0; r < 4; ++r) {
                bool ok = (!((chosen >> r) & 1u)) && (kr[r] < localk);
                localk = ok ? kr[r] : localk;
                br = ok ? r : br;
            }
            const unsigned mybits = (unsigned)(localk >> 32);
            const unsigned myidx = (unsigned)localk;
            unsigned wb = mybits;
            DPP_UMIN_STEP_V(wb, 0x111, 0xF)
            DPP_UMIN_STEP_V(wb, 0x112, 0xF)
            DPP_UMIN_STEP_V(wb, 0x114, 0xF)
            DPP_UMIN_STEP_V(wb, 0x118, 0xF)
            DPP_UMIN_STEP_V(wb, 0x142, 0xA)
            DPP_UMIN_STEP_V(wb, 0x143, 0xC)
            const unsigned minbits = (unsigned)__builtin_amdgcn_readlane((int)wb, 63);
            const unsigned long long wmask = __ballot(mybits == minbits);
            unsigned widx;
            if (__popcll(wmask) == 1) {
                const int wl = __ffsll((long long)wmask) - 1;
                widx = (unsigned)__builtin_amdgcn_readlane((int)myidx, wl);
            } else {
                unsigned cand = (mybits == minbits) ? myidx : 0xFFFFFFFFu;
                DPP_UMIN_STEP(0x111, 0xF)
                DPP_UMIN_STEP(0x112, 0xF)
                DPP_UMIN_STEP(0x114, 0xF)
                DPP_UMIN_STEP(0x118, 0xF)
                DPP_UMIN_STEP(0x142, 0xA)
                DPP_UMIN_STEP(0x143, 0xC)
                widx = (unsigned)__builtin_amdgcn_readlane((int)cand, 63);
            }
            if (mybits == minbits && myidx == widx) chosen |= 1u << br;
            if (lane == 0) nbr[s * K_ + k] = (int)widx;
        }
    } else {
        // exact fallback (rare): LDS-scan selection with u64 DPP min
        unsigned chosen = 0;
        for (int k = 0; k < kcnt; ++k) {
            unsigned long long localk = ~0ull; int bslot = -1;
            for (int r = 0; r * 64 + lane < m; ++r) {
                if (chosen & (1u << r)) continue;
                int q = r * 64 + lane;
                unsigned long long key = ck[w][q];
                if (key < localk) { localk = key; bslot = q; }
            }
            unsigned kh = (unsigned)(localk >> 32), kl = (unsigned)localk;
#define DPP_MIN_STEP2(CTRL, RM)                                           \
            {                                                             \
                unsigned nh = dppmov<CTRL, RM>(kh);                       \
                unsigned nl = dppmov<CTRL, RM>(kl);                       \
                unsigned long long nk = (((unsigned long long)nh) << 32) | nl; \
                unsigned long long ok = (((unsigned long long)kh) << 32) | kl; \
                if (nk < ok) { kh = nh; kl = nl; }                        \
            }
            DPP_MIN_STEP2(0x111, 0xF)
            DPP_MIN_STEP2(0x112, 0xF)
            DPP_MIN_STEP2(0x114, 0xF)
            DPP_MIN_STEP2(0x118, 0xF)
            DPP_MIN_STEP2(0x142, 0xA)
            DPP_MIN_STEP2(0x143, 0xC)
#undef DPP_MIN_STEP2
            unsigned mh = (unsigned)__builtin_amdgcn_readlane((int)kh, 63);
            unsigned ml = (unsigned)__builtin_amdgcn_readlane((int)kl, 63);
            unsigned long long bk = (((unsigned long long)mh) << 32) | ml;
            if (localk == bk && bslot >= 0) chosen |= 1u << (bslot >> 6);
            if (lane == 0) nbr[s * K_ + k] = (int)(bk & 0xFFFFFFFFull);
        }
    }
    if (lane == 0) {
        for (int k = kcnt; k < K_; ++k) nbr[s * K_ + k] = -1;
        cntv[s] = (float)kcnt;
    }
}

// ---------------- message MLP v5: bf16 MFMA, pre-converted x ----------------
__global__ __launch_bounds__(256) void msg_kernel(
    const ushort_t* __restrict__ xb, const float* __restrict__ pos,
    const float* __restrict__ W1, const float* __restrict__ b1,
    const float* __restrict__ W2, const float* __restrict__ b2,
    const float* __restrict__ pos_s, const int* __restrict__ nbr,
    const float* __restrict__ cntv, float* __restrict__ aggr_x,
    float* __restrict__ out_pos)
{
    __shared__ __align__(16) char smem[4 * 5120];
    const int t = threadIdx.x;
    const int wv = t >> 6, lane = t & 63;
    const int quad = lane >> 4, cl = lane & 15;
    char* wb = smem + wv * 5120;

    short8 bfrag[8][2];
    float b1v[8], w1dv[8], w2v0[8], w2v1[8], w2v2[8];
#pragma unroll
    for (int Nt = 0; Nt < 8; ++Nt) {
        const int h = Nt * 16 + cl;
#pragma unroll
        for (int ks = 0; ks < 2; ++ks) {
            short8 f;
#pragma unroll
            for (int jj = 0; jj < 8; ++jj)
                f[jj] = f2bf(W1[(ks * 32 + quad * 8 + jj) * H_ + h]);
            bfrag[Nt][ks] = f;
        }
        b1v[Nt] = b1[h];
        w1dv[Nt] = W1[64 * H_ + h];
        w2v0[Nt] = W2[h * 3 + 0];
        w2v1[Nt] = W2[h * 3 + 1];
        w2v2[Nt] = W2[h * 3 + 2];
    }
    const float b20 = b2[0], b21 = b2[1], b22 = b2[2];

    const int kkg = lane >> 1, half = lane & 1;
    for (int i = 0; i < 4; ++i) {
        const int s = blockIdx.x * 16 + wv * 4 + i;
        const int b = s >> 10;
        const int n = nbr[s * K_ + kkg];
        {
            char* frow = wb + kkg * 144 + half * 64;
            if (n >= 0) {
                const short8* xr = (const short8*)(xb + ((size_t)b * N_ + n) * D_) + half * 4;
#pragma unroll
                for (int q = 0; q < 4; ++q) *(short8*)(frow + q * 16) = xr[q];
            } else {
                short8 z = {0, 0, 0, 0, 0, 0, 0, 0};
#pragma unroll
                for (int q = 0; q < 4; ++q) *(short8*)(frow + q * 16) = z;
            }
            if (half == 0) {
                float dxm = 0.f, dym = 0.f, dzm = 0.f, de = -1.f;
                if (n >= 0) {
                    const float* pj = pos + ((size_t)b * N_ + n) * 3;
                    float dx = pj[0] - pos_s[s * 3 + 0];
                    float dy = pj[1] - pos_s[s * 3 + 1];
                    float dz = pj[2] - pos_s[s * 3 + 2];
                    float d2 = dx * dx + dy * dy + dz * dz;
                    de = d2 > 0.f ? sqrtf(d2) : 0.f;
                    dxm = dx; dym = dy; dzm = dz;
                }
                f32x4 sv = {dxm, dym, dzm, de};
                *(f32x4*)(wb + 4608 + kkg * 16) = sv;
            }
        }
        float agp[8] = {0, 0, 0, 0, 0, 0, 0, 0};
        float gp0[8] = {0, 0, 0, 0, 0, 0, 0, 0};
        float gp1[8] = {0, 0, 0, 0, 0, 0, 0, 0};
        float gp2[8] = {0, 0, 0, 0, 0, 0, 0, 0};
#pragma unroll
        for (int Mt = 0; Mt < 2; ++Mt) {
            short8 a0 = *(short8*)(wb + (Mt * 16 + cl) * 144 + quad * 16);
            short8 a1 = *(short8*)(wb + (Mt * 16 + cl) * 144 + 64 + quad * 16);
            f32x4 acc[8];
#pragma unroll
            for (int Nt = 0; Nt < 8; ++Nt) {
                f32x4 z = {0.f, 0.f, 0.f, 0.f};
                z = __builtin_amdgcn_mfma_f32_16x16x32_bf16(a0, bfrag[Nt][0], z, 0, 0, 0);
                z = __builtin_amdgcn_mfma_f32_16x16x32_bf16(a1, bfrag[Nt][1], z, 0, 0, 0);
                acc[Nt] = z;
            }
            f32x4 sd[4];
#pragma unroll
            for (int r = 0; r < 4; ++r)
                sd[r] = *(f32x4*)(wb + 4608 + (Mt * 16 + quad * 4 + r) * 16);
#pragma unroll
            for (int Nt = 0; Nt < 8; ++Nt) {
#pragma unroll
                for (int r = 0; r < 4; ++r) {
                    float dr = sd[r][3];
                    float wgt = dr >= 0.f ? 1.f : 0.f;
                    float dd = dr >= 0.f ? dr : 0.f;
                    float e = fmaf(dd, w1dv[Nt], acc[Nt][r]) + b1v[Nt];
                    e = e > 0.f ? e : 0.f;
                    agp[Nt] = fmaf(wgt, e, agp[Nt]);
                    gp0[Nt] = fmaf(sd[r][0], e, gp0[Nt]);
                    gp1[Nt] = fmaf(sd[r][1], e, gp1[Nt]);
                    gp2[Nt] = fmaf(sd[r][2], e, gp2[Nt]);
                }
            }
        }
#pragma unroll
        for (int Nt = 0; Nt < 8; ++Nt) {
            float v = agp[Nt]; v += __shfl_xor(v, 16); v += __shfl_xor(v, 32);
            aggr_x[(size_t)s * H_ + Nt * 16 + cl] = v;
            float g0 = gp0[Nt]; g0 += __shfl_xor(g0, 16); g0 += __shfl_xor(g0, 32); gp0[Nt] = g0;
            float g1 = gp1[Nt]; g1 += __shfl_xor(g1, 16); g1 += __shfl_xor(g1, 32); gp1[Nt] = g1;
            float g2 = gp2[Nt]; g2 += __shfl_xor(g2, 16); g2 += __shfl_xor(g2, 32); gp2[Nt] = g2;
        }
        float pr0 = 0.f, pr1 = 0.f, pr2 = 0.f;
#pragma unroll
        for (int Nt = 0; Nt < 8; ++Nt) {
            pr0 = fmaf(w2v0[Nt], gp0[Nt], pr0);
            pr1 = fmaf(w2v1[Nt], gp1[Nt], pr1);
            pr2 = fmaf(w2v2[Nt], gp2[Nt], pr2);
        }
#pragma unroll
        for (int off = 1; off < 16; off <<= 1) {
            pr0 += __shfl_xor(pr0, off);
            pr1 += __shfl_xor(pr1, off);
            pr2 += __shfl_xor(pr2, off);
        }
        f32x4 dsv = *(f32x4*)(wb + 4608 + (lane & 31) * 16);
        float q0 = dsv[0], q1 = dsv[1], q2 = dsv[2];
#pragma unroll
        for (int off = 1; off < 32; off <<= 1) {
            q0 += __shfl_xor(q0, off);
            q1 += __shfl_xor(q1, off);
            q2 += __shfl_xor(q2, off);
        }
        float cnt = cntv[s]; if (cnt < 1.f) cnt = 1.f;
        if (lane < 3) {
            float pr = lane == 0 ? pr0 : (lane == 1 ? pr1 : pr2);
            float qq = lane == 0 ? q0 : (lane == 1 ? q1 : q2);
            float bb = lane == 0 ? b20 : (lane == 1 ? b21 : b22);
            out_pos[s * 3 + lane] = pos_s[s * 3 + lane] + (pr + bb * qq) / cnt;
        }
    }
}

// ---------------- update GEMM: relu([x_d, aggr_x] @ W3 + b3) ----------------
__global__ __launch_bounds__(128) void out_kernel(
    const float* __restrict__ x, const float* __restrict__ W3,
    const float* __restrict__ b3, const int* __restrict__ idx_i,
    const float* __restrict__ aggr_x, float* __restrict__ out_x)
{
    __shared__ float rows[32][208];
    const int t = threadIdx.x;
    const int s0 = blockIdx.x * 32;
    const int sl = t >> 2, part = t & 3;
    const int s = s0 + sl;
    const int b = s >> 10;
    const int id = idx_i[s];
    {
        const float4* xr = (const float4*)(x + ((size_t)b * N_ + id) * D_);
        float4* rr = (float4*)&rows[sl][0];
#pragma unroll
        for (int q = 0; q < 4; ++q) rr[part * 4 + q] = xr[part * 4 + q];
        const float4* ar = (const float4*)(aggr_x + (size_t)s * H_);
        float4* rr2 = (float4*)&rows[sl][64];
#pragma unroll
        for (int q = 0; q < 8; ++q) rr2[part * 8 + q] = ar[part * 8 + q];
    }
    __syncthreads();
    float acc[32];
#pragma unroll
    for (int i = 0; i < 32; ++i) acc[i] = 0.f;
    for (int j4 = 0; j4 < 48; ++j4) {
        float w0 = W3[(j4 * 4 + 0) * H_ + t];
        float w1 = W3[(j4 * 4 + 1) * H_ + t];
        float w2 = W3[(j4 * 4 + 2) * H_ + t];
        float w3 = W3[(j4 * 4 + 3) * H_ + t];
#pragma unroll
        for (int i = 0; i < 32; ++i) {
            const float4 f = *(const float4*)&rows[i][j4 * 4];
            float a = acc[i];
            a = fmaf(f.x, w0, a); a = fmaf(f.y, w1, a);
            a = fmaf(f.z, w2, a); a = fmaf(f.w, w3, a);
            acc[i] = a;
        }
    }
    const float bb = b3[t];
#pragma unroll
    for (int i = 0; i < 32; ++i) {
        float v = acc[i] + bb;
        v = v > 0.f ? v : 0.f;
        out_x[(size_t)(s0 + i) * H_ + t] = v;
    }
}

extern "C" void kernel_launch(void* const* d_in, const int* in_sizes, int n_in,
                              void* d_out, int out_size, void* d_ws, size_t ws_size,
                              hipStream_t stream) {
    const float* x   = (const float*)d_in[0];
    const float* pos = (const float*)d_in[1];
    const float* W1  = (const float*)d_in[2];
    const float* b1  = (const float*)d_in[3];
    const float* W2  = (const float*)d_in[4];
    const float* b2  = (const float*)d_in[5];
    const float* W3  = (const float*)d_in[6];
    const float* b3  = (const float*)d_in[7];

    float* out_x   = (float*)d_out;                       // [16,1024,128]
    float* out_pos = (float*)d_out + 2097152;             // [16,1024,3]
    float* idx_f   = (float*)d_out + 2146304;             // [16,1024] as float

    char* ws = (char*)d_ws;
    int*      idx_i  = (int*)ws;                   // 16384 ints
    float*    pos_s  = (float*)(ws + 65536);       // 49152 floats
    int*      nbr    = (int*)(ws + 262144);        // 524288 ints
    float*    cntv   = (float*)(ws + 2359296);     // 16384 floats
    float*    aggr_x = (float*)(ws + 2424832);     // 2097152 floats
    ushort_t* x_bf16 = (ushort_t*)(ws + 10813440); // 16777216 ushorts (ends ~19.2MB)

    // fps blocks 0..15 + fused cvt blocks 16..2063 (cvt hidden under fps)
    fps_kernel<<<B_ + (B_ * N_ * D_) / (256 * 8), 256, 0, stream>>>(
        pos, idx_i, idx_f, pos_s, x, x_bf16);
    nbr_kernel<<<(B_ * NS_) / 4, 256, 0, stream>>>(pos, pos_s, nbr, cntv);
    msg_kernel<<<(B_ * NS_) / 16, 256, 0, stream>>>(x_bf16, pos, W1, b1, W2, b2,
                                                    pos_s, nbr, cntv, aggr_x, out_pos);
    out_kernel<<<(B_ * NS_) / 32, 128, 0, stream>>>(x, W3, b3, idx_i, aggr_x, out_x);
}

// Round 7
// 920.521 us; speedup vs baseline: 1.3089x; 1.0686x over previous
//
#include <hip/hip_runtime.h>
#include <math.h>

#define B_ 16
#define N_ 4096
#define D_ 64
#define H_ 128
#define K_ 32
#define NS_ 1024
#define R2_ 0.04f
#define NCAP_ 256
#define NBR_GRID_ ((B_ * NS_) / 4)

typedef short short8 __attribute__((ext_vector_type(8)));
typedef float f32x4 __attribute__((ext_vector_type(4)));
typedef unsigned short ushort_t;

static __device__ __forceinline__ short f2bf(float f) {
    unsigned u = __float_as_uint(f);
    unsigned r = (u + 0x7FFFu + ((u >> 16) & 1u)) >> 16;   // round-to-nearest-even
    return (short)r;
}

template<int CTRL, int RM>
static __device__ __forceinline__ unsigned dppmov(unsigned v) {
    // old = v -> masked/invalid lanes keep v (identity for max/min)
    return (unsigned)__builtin_amdgcn_update_dpp((int)v, (int)v, CTRL, RM, 0xF, false);
}

#define DPP_FMAX_STEP(CTRL, RM)                                           \
    {                                                                     \
        float n = __uint_as_float(dppmov<CTRL, RM>(__float_as_uint(wm))); \
        wm = fmaxf(wm, n);                                                \
    }

#define DPP_UMIN_STEP(CTRL, RM)                                           \
    {                                                                     \
        unsigned n = dppmov<CTRL, RM>(cand);                              \
        cand = n < cand ? n : cand;                                       \
    }

#define DPP_UMIN_STEP_V(var, CTRL, RM)                                    \
    {                                                                     \
        unsigned n = dppmov<CTRL, RM>(var);                               \
        var = n < var ? n : var;                                          \
    }

// ---------------- FPS v8 (verbatim R0 baseline, 647us measured) -----------
__global__ __launch_bounds__(256, 1) void fps_kernel(
    const float* __restrict__ pos, int* __restrict__ idx_i,
    float* __restrict__ idx_f, float* __restrict__ pos_s)
{
    __shared__ float4 lpos4[N_];                         // 64 KB
    __shared__ float4 sres[NS_];                         // 16 KB
    __shared__ unsigned long long skey[2][4];
    __shared__ float4 scoord[2][4];
    const int b = blockIdx.x;
    const int t = threadIdx.x;
    const int wv = t >> 6;
    const int lane = t & 63;
    const float* posb = pos + (size_t)b * N_ * 3;
    for (int p = t; p < N_; p += 256)
        lpos4[p] = make_float4(posb[3 * p + 0], posb[3 * p + 1], posb[3 * p + 2], 0.f);
    __syncthreads();

    float px[16], py[16], pz[16], dist[16];
#pragma unroll
    for (int j = 0; j < 16; ++j) {
        float4 v = lpos4[t + 256 * j];
        px[j] = v.x; py[j] = v.y; pz[j] = v.z;
        dist[j] = 1e10f;
    }
    unsigned curidx = 0;
    float4 c0 = lpos4[0];
    float ccx = c0.x, ccy = c0.y, ccz = c0.z;

    for (int ns = 0; ns < NS_; ++ns) {
        if (t == 0)
            sres[ns] = make_float4(ccx, ccy, ccz, __uint_as_float(curidx));
        // ---- update dists + per-lane argmax (bit-exact d2 chain) ----
        float bv = -1.f; int bj = 0;
#pragma unroll
        for (int j = 0; j < 16; ++j) {
            float dx = __fsub_rn(px[j], ccx);
            float dy = __fsub_rn(py[j], ccy);
            float dz = __fsub_rn(pz[j], ccz);
            float d2 = __fadd_rn(__fadd_rn(__fmul_rn(dx, dx), __fmul_rn(dy, dy)), __fmul_rn(dz, dz));
            float dn = fminf(dist[j], d2);
            dist[j] = dn;
            bool g = dn > bv;                 // strict > + ascending j => lowest idx on tie
            bv = g ? dn : bv;
            bj = g ? j : bj;
        }
        // ---- wave fp32 max via DPP (result valid in lane 63) ----
        float wm = bv;
        DPP_FMAX_STEP(0x111, 0xF)   // row_shr:1
        DPP_FMAX_STEP(0x112, 0xF)   // row_shr:2
        DPP_FMAX_STEP(0x114, 0xF)   // row_shr:4
        DPP_FMAX_STEP(0x118, 0xF)   // row_shr:8
        DPP_FMAX_STEP(0x142, 0xA)   // row_bcast:15
        DPP_FMAX_STEP(0x143, 0xC)   // row_bcast:31
        const float wavemax = __uint_as_float(
            (unsigned)__builtin_amdgcn_readlane((int)__float_as_uint(wm), 63));
        // ---- min global idx among max-achieving lanes ----
        const unsigned pidx = (unsigned)t + ((unsigned)bj << 8);   // == global point idx
        const unsigned long long mask = __ballot(bv == wavemax);
        unsigned widx;
        if (__popcll(mask) == 1) {             // unique winner (common case)
            const int wl = __ffsll((long long)mask) - 1;
            widx = (unsigned)__builtin_amdgcn_readlane((int)pidx, wl);
        } else {                                // exact tie fallback
            unsigned cand = (bv == wavemax) ? pidx : 0xFFFFFFFFu;
            DPP_UMIN_STEP(0x111, 0xF)
            DPP_UMIN_STEP(0x112, 0xF)
            DPP_UMIN_STEP(0x114, 0xF)
            DPP_UMIN_STEP(0x118, 0xF)
            DPP_UMIN_STEP(0x142, 0xA)
            DPP_UMIN_STEP(0x143, 0xC)
            widx = (unsigned)__builtin_amdgcn_readlane((int)cand, 63);
        }
        // prefetch this wave's winner coords (broadcast, uniform addr) so the
        // coord fetch latency hides under the key store + barrier wait
        float4 wc = lpos4[widx];
        if (lane == 0) {
            skey[ns & 1][wv] = (((unsigned long long)__float_as_uint(wavemax)) << 32)
                             | (unsigned long long)(0xFFFFFFFFu - widx);
            scoord[ns & 1][wv] = wc;
        }
        __syncthreads();
        // ---- 4-slot u64-max tournament (carrying slot id); coords via
        //      v_readlane from the slot-holder lane (no second LDS read) ----
        {
            unsigned sid = (unsigned)(lane & 3);
            unsigned long long skv = skey[ns & 1][sid];
            float4 scv = scoord[ns & 1][sid];
            unsigned kh2 = (unsigned)(skv >> 32), kl2 = (unsigned)skv;
#define SLOT_STEP(CTRL)                                                        \
            {                                                                  \
                unsigned nh = dppmov<CTRL, 0xF>(kh2);                          \
                unsigned nl = dppmov<CTRL, 0xF>(kl2);                          \
                unsigned nsid = dppmov<CTRL, 0xF>(sid);                        \
                unsigned long long nk = (((unsigned long long)nh) << 32) | nl; \
                unsigned long long ok = (((unsigned long long)kh2) << 32) | kl2;\
                if (nk > ok) { kh2 = nh; kl2 = nl; sid = nsid; }               \
            }
            SLOT_STEP(0x101)   // row_shl:1
            SLOT_STEP(0x102)   // row_shl:2
#undef SLOT_STEP
            const int slotwin = __builtin_amdgcn_readfirstlane((int)sid);
            curidx = 0xFFFFFFFFu - (unsigned)__builtin_amdgcn_readfirstlane((int)kl2);
            ccx = __uint_as_float((unsigned)__builtin_amdgcn_readlane(
                      (int)__float_as_uint(scv.x), slotwin));
            ccy = __uint_as_float((unsigned)__builtin_amdgcn_readlane(
                      (int)__float_as_uint(scv.y), slotwin));
            ccz = __uint_as_float((unsigned)__builtin_amdgcn_readlane(
                      (int)__float_as_uint(scv.z), slotwin));
        }
    }
    __syncthreads();
    for (int i = t; i < NS_; i += 256) {
        float4 r = sres[i];
        unsigned id = __float_as_uint(r.w);
        idx_i[b * NS_ + i] = (int)id;
        idx_f[b * NS_ + i] = (float)id;
        pos_s[(b * NS_ + i) * 3 + 0] = r.x;
        pos_s[(b * NS_ + i) * 3 + 1] = r.y;
        pos_s[(b * NS_ + i) * 3 + 2] = r.z;
    }
}

// ---------------- radius-KNN v6: 8KB candidate buffer + fused cvt ----------
// Changes vs v5 (both counter-backed, R6 profile: LDS 32KB -> 5 blocks/CU,
// Occupancy 13%, VALUBusy 17% = latency-bound):
//  * ck shrunk [4][1024] -> [4][256] (8KB): hot path only reads slots <256.
//    LDS cap 5 -> 8 blocks/CU (32/32 waves). m>256 (P ~ 1e-20 for
//    Poisson(137) in-radius counts) handled by an exact lexicographic
//    successive-min rescan (keys (d2<<32|p) strictly increasing; identical
//    d2 chain and tie rule; considers ALL in-radius points, no 1024 cap).
//  * blocks >= 4096 run the x->bf16 pre-convert (R5-validated fusion
//    mechanism, moved off the latency-critical fps onto this throughput
//    kernel). nbr blocks dispatch first; cvt traffic hides in the makespan;
//    x_bf16 complete before msg by stream order.
__global__ __launch_bounds__(256) void nbr_kernel(
    const float* __restrict__ pos, const float* __restrict__ pos_s,
    int* __restrict__ nbr, float* __restrict__ cntv,
    const float* __restrict__ x, ushort_t* __restrict__ xb)
{
    __shared__ unsigned long long ck[4][NCAP_];
    if (blockIdx.x >= NBR_GRID_) {
        // ---- fused cvt branch (block-uniform; no barriers executed) ----
        const size_t i = ((size_t)(blockIdx.x - NBR_GRID_) * 256 + threadIdx.x) * 8;
        float4 a = *(const float4*)(x + i);
        float4 c = *(const float4*)(x + i + 4);
        short8 o;
        o[0] = f2bf(a.x); o[1] = f2bf(a.y); o[2] = f2bf(a.z); o[3] = f2bf(a.w);
        o[4] = f2bf(c.x); o[5] = f2bf(c.y); o[6] = f2bf(c.z); o[7] = f2bf(c.w);
        *(short8*)(xb + i) = o;
        return;
    }
    const int w = threadIdx.x >> 6;
    const int lane = threadIdx.x & 63;
    const int s = blockIdx.x * 4 + w;
    const int b = s >> 10;
    const float cx = pos_s[s * 3 + 0], cy = pos_s[s * 3 + 1], cz = pos_s[s * 3 + 2];
    const float* posb = pos + (size_t)b * N_ * 3;
    int m = 0;
    for (int base = 0; base < N_; base += 64) {
        int p = base + lane;
        float dx = __fsub_rn(posb[3 * p + 0], cx);
        float dy = __fsub_rn(posb[3 * p + 1], cy);
        float dz = __fsub_rn(posb[3 * p + 2], cz);
        float d2 = __fadd_rn(__fadd_rn(__fmul_rn(dx, dx), __fmul_rn(dy, dy)), __fmul_rn(dz, dz));
        bool in = (d2 <= R2_);
        unsigned long long msk = __ballot(in);
        int before = __popcll(msk & ((1ull << lane) - 1ull));
        int slot = m + before;
        if (in && slot < NCAP_)
            ck[w][slot] = ((unsigned long long)__float_as_uint(d2) << 32) | (unsigned)p;
        m += __popcll(msk);
    }
    __asm__ volatile("s_waitcnt lgkmcnt(0)" ::: "memory");
    int kcnt = m < K_ ? m : K_;
    if (m <= NCAP_) {
        // register-resident candidates; selection = u64 local scan +
        // u32 d2-min DPP + ballot winner (exact idx-umin fallback on ties)
        unsigned long long kr[4];
#pragma unroll
        for (int r = 0; r < 4; ++r) {
            int q = r * 64 + lane;
            unsigned long long v = ck[w][q & (NCAP_ - 1)];
            kr[r] = (q < m) ? v : ~0ull;
        }
        unsigned chosen = 0;
        for (int k = 0; k < kcnt; ++k) {
            unsigned long long localk = ~0ull; int br = -1;
#pragma unroll
            for (int r = 0; r < 4; ++r) {
                bool ok = (!((chosen >> r) & 1u)) && (kr[r] < localk);
                localk = ok ? kr[r] : localk;
                br = ok ? r : br;
            }
            const unsigned mybits = (unsigned)(localk >> 32);
            const unsigned myidx = (unsigned)localk;
            unsigned wb = mybits;
            DPP_UMIN_STEP_V(wb, 0x111, 0xF)
            DPP_UMIN_STEP_V(wb, 0x112, 0xF)
            DPP_UMIN_STEP_V(wb, 0x114, 0xF)
            DPP_UMIN_STEP_V(wb, 0x118, 0xF)
            DPP_UMIN_STEP_V(wb, 0x142, 0xA)
            DPP_UMIN_STEP_V(wb, 0x143, 0xC)
            const unsigned minbits = (unsigned)__builtin_amdgcn_readlane((int)wb, 63);
            const unsigned long long wmask = __ballot(mybits == minbits);
            unsigned widx;
            if (__popcll(wmask) == 1) {
                const int wl = __ffsll((long long)wmask) - 1;
                widx = (unsigned)__builtin_amdgcn_readlane((int)myidx, wl);
            } else {
                unsigned cand = (mybits == minbits) ? myidx : 0xFFFFFFFFu;
                DPP_UMIN_STEP(0x111, 0xF)
                DPP_UMIN_STEP(0x112, 0xF)
                DPP_UMIN_STEP(0x114, 0xF)
                DPP_UMIN_STEP(0x118, 0xF)
                DPP_UMIN_STEP(0x142, 0xA)
                DPP_UMIN_STEP(0x143, 0xC)
                widx = (unsigned)__builtin_amdgcn_readlane((int)cand, 63);
            }
            if (mybits == minbits && myidx == widx) chosen |= 1u << br;
            if (lane == 0) nbr[s * K_ + k] = (int)widx;
        }
    } else {
        // ultra-rare exact fallback (m > 256): successive lexicographic
        // minima by full rescan. Keys (d2<<32|p) are unique & totally
        // ordered; k-th neighbor = min key >= prev. Same d2 chain, same
        // lowest-idx-on-tie rule; considers ALL in-radius points.
        unsigned long long prev = 0ull;
        for (int k = 0; k < kcnt; ++k) {
            unsigned long long localk = ~0ull;
            for (int base = 0; base < N_; base += 64) {
                int p = base + lane;
                float dx = __fsub_rn(posb[3 * p + 0], cx);
                float dy = __fsub_rn(posb[3 * p + 1], cy);
                float dz = __fsub_rn(posb[3 * p + 2], cz);
                float d2 = __fadd_rn(__fadd_rn(__fmul_rn(dx, dx), __fmul_rn(dy, dy)), __fmul_rn(dz, dz));
                if (d2 <= R2_) {
                    unsigned long long key =
                        ((unsigned long long)__float_as_uint(d2) << 32) | (unsigned)p;
                    if (key >= prev && key < localk) localk = key;
                }
            }
            unsigned kh = (unsigned)(localk >> 32), kl = (unsigned)localk;
#define DPP_MIN_STEP2(CTRL, RM)                                           \
            {                                                             \
                unsigned nh = dppmov<CTRL, RM>(kh);                       \
                unsigned nl = dppmov<CTRL, RM>(kl);                       \
                unsigned long long nk = (((unsigned long long)nh) << 32) | nl; \
                unsigned long long ok = (((unsigned long long)kh) << 32) | kl; \
                if (nk < ok) { kh = nh; kl = nl; }                        \
            }
            DPP_MIN_STEP2(0x111, 0xF)
            DPP_MIN_STEP2(0x112, 0xF)
            DPP_MIN_STEP2(0x114, 0xF)
            DPP_MIN_STEP2(0x118, 0xF)
            DPP_MIN_STEP2(0x142, 0xA)
            DPP_MIN_STEP2(0x143, 0xC)
#undef DPP_MIN_STEP2
            unsigned mh = (unsigned)__builtin_amdgcn_readlane((int)kh, 63);
            unsigned ml = (unsigned)__builtin_amdgcn_readlane((int)kl, 63);
            unsigned long long bk = (((unsigned long long)mh) << 32) | ml;
            prev = bk + 1ull;
            if (lane == 0) nbr[s * K_ + k] = (int)(bk & 0xFFFFFFFFull);
        }
    }
    if (lane == 0) {
        for (int k = kcnt; k < K_; ++k) nbr[s * K_ + k] = -1;
        cntv[s] = (float)kcnt;
    }
}

// ---------------- message MLP v5: bf16 MFMA, pre-converted x ----------------
__global__ __launch_bounds__(256) void msg_kernel(
    const ushort_t* __restrict__ xb, const float* __restrict__ pos,
    const float* __restrict__ W1, const float* __restrict__ b1,
    const float* __restrict__ W2, const float* __restrict__ b2,
    const float* __restrict__ pos_s, const int* __restrict__ nbr,
    const float* __restrict__ cntv, float* __restrict__ aggr_x,
    float* __restrict__ out_pos)
{
    __shared__ __align__(16) char smem[4 * 5120];
    const int t = threadIdx.x;
    const int wv = t >> 6, lane = t & 63;
    const int quad = lane >> 4, cl = lane & 15;
    char* wb = smem + wv * 5120;

    short8 bfrag[8][2];
    float b1v[8], w1dv[8], w2v0[8], w2v1[8], w2v2[8];
#pragma unroll
    for (int Nt = 0; Nt < 8; ++Nt) {
        const int h = Nt * 16 + cl;
#pragma unroll
        for (int ks = 0; ks < 2; ++ks) {
            short8 f;
#pragma unroll
            for (int jj = 0; jj < 8; ++jj)
                f[jj] = f2bf(W1[(ks * 32 + quad * 8 + jj) * H_ + h]);
            bfrag[Nt][ks] = f;
        }
        b1v[Nt] = b1[h];
        w1dv[Nt] = W1[64 * H_ + h];
        w2v0[Nt] = W2[h * 3 + 0];
        w2v1[Nt] = W2[h * 3 + 1];
        w2v2[Nt] = W2[h * 3 + 2];
    }
    const float b20 = b2[0], b21 = b2[1], b22 = b2[2];

    const int kkg = lane >> 1, half = lane & 1;
    for (int i = 0; i < 4; ++i) {
        const int s = blockIdx.x * 16 + wv * 4 + i;
        const int b = s >> 10;
        const int n = nbr[s * K_ + kkg];
        {
            char* frow = wb + kkg * 144 + half * 64;
            if (n >= 0) {
                const short8* xr = (const short8*)(xb + ((size_t)b * N_ + n) * D_) + half * 4;
#pragma unroll
                for (int q = 0; q < 4; ++q) *(short8*)(frow + q * 16) = xr[q];
            } else {
                short8 z = {0, 0, 0, 0, 0, 0, 0, 0};
#pragma unroll
                for (int q = 0; q < 4; ++q) *(short8*)(frow + q * 16) = z;
            }
            if (half == 0) {
                float dxm = 0.f, dym = 0.f, dzm = 0.f, de = -1.f;
                if (n >= 0) {
                    const float* pj = pos + ((size_t)b * N_ + n) * 3;
                    float dx = pj[0] - pos_s[s * 3 + 0];
                    float dy = pj[1] - pos_s[s * 3 + 1];
                    float dz = pj[2] - pos_s[s * 3 + 2];
                    float d2 = dx * dx + dy * dy + dz * dz;
                    de = d2 > 0.f ? sqrtf(d2) : 0.f;
                    dxm = dx; dym = dy; dzm = dz;
                }
                f32x4 sv = {dxm, dym, dzm, de};
                *(f32x4*)(wb + 4608 + kkg * 16) = sv;
            }
        }
        float agp[8] = {0, 0, 0, 0, 0, 0, 0, 0};
        float gp0[8] = {0, 0, 0, 0, 0, 0, 0, 0};
        float gp1[8] = {0, 0, 0, 0, 0, 0, 0, 0};
        float gp2[8] = {0, 0, 0, 0, 0, 0, 0, 0};
#pragma unroll
        for (int Mt = 0; Mt < 2; ++Mt) {
            short8 a0 = *(short8*)(wb + (Mt * 16 + cl) * 144 + quad * 16);
            short8 a1 = *(short8*)(wb + (Mt * 16 + cl) * 144 + 64 + quad * 16);
            f32x4 acc[8];
#pragma unroll
            for (int Nt = 0; Nt < 8; ++Nt) {
                f32x4 z = {0.f, 0.f, 0.f, 0.f};
                z = __builtin_amdgcn_mfma_f32_16x16x32_bf16(a0, bfrag[Nt][0], z, 0, 0, 0);
                z = __builtin_amdgcn_mfma_f32_16x16x32_bf16(a1, bfrag[Nt][1], z, 0, 0, 0);
                acc[Nt] = z;
            }
            f32x4 sd[4];
#pragma unroll
            for (int r = 0; r < 4; ++r)
                sd[r] = *(f32x4*)(wb + 4608 + (Mt * 16 + quad * 4 + r) * 16);
#pragma unroll
            for (int Nt = 0; Nt < 8; ++Nt) {
#pragma unroll
                for (int r = 0; r < 4; ++r) {
                    float dr = sd[r][3];
                    float wgt = dr >= 0.f ? 1.f : 0.f;
                    float dd = dr >= 0.f ? dr : 0.f;
                    float e = fmaf(dd, w1dv[Nt], acc[Nt][r]) + b1v[Nt];
                    e = e > 0.f ? e : 0.f;
                    agp[Nt] = fmaf(wgt, e, agp[Nt]);
                    gp0[Nt] = fmaf(sd[r][0], e, gp0[Nt]);
                    gp1[Nt] = fmaf(sd[r][1], e, gp1[Nt]);
                    gp2[Nt] = fmaf(sd[r][2], e, gp2[Nt]);
                }
            }
        }
#pragma unroll
        for (int Nt = 0; Nt < 8; ++Nt) {
            float v = agp[Nt]; v += __shfl_xor(v, 16); v += __shfl_xor(v, 32);
            aggr_x[(size_t)s * H_ + Nt * 16 + cl] = v;
            float g0 = gp0[Nt]; g0 += __shfl_xor(g0, 16); g0 += __shfl_xor(g0, 32); gp0[Nt] = g0;
            float g1 = gp1[Nt]; g1 += __shfl_xor(g1, 16); g1 += __shfl_xor(g1, 32); gp1[Nt] = g1;
            float g2 = gp2[Nt]; g2 += __shfl_xor(g2, 16); g2 += __shfl_xor(g2, 32); gp2[Nt] = g2;
        }
        float pr0 = 0.f, pr1 = 0.f, pr2 = 0.f;
#pragma unroll
        for (int Nt = 0; Nt < 8; ++Nt) {
            pr0 = fmaf(w2v0[Nt], gp0[Nt], pr0);
            pr1 = fmaf(w2v1[Nt], gp1[Nt], pr1);
            pr2 = fmaf(w2v2[Nt], gp2[Nt], pr2);
        }
#pragma unroll
        for (int off = 1; off < 16; off <<= 1) {
            pr0 += __shfl_xor(pr0, off);
            pr1 += __shfl_xor(pr1, off);
            pr2 += __shfl_xor(pr2, off);
        }
        f32x4 dsv = *(f32x4*)(wb + 4608 + (lane & 31) * 16);
        float q0 = dsv[0], q1 = dsv[1], q2 = dsv[2];
#pragma unroll
        for (int off = 1; off < 32; off <<= 1) {
            q0 += __shfl_xor(q0, off);
            q1 += __shfl_xor(q1, off);
            q2 += __shfl_xor(q2, off);
        }
        float cnt = cntv[s]; if (cnt < 1.f) cnt = 1.f;
        if (lane < 3) {
            float pr = lane == 0 ? pr0 : (lane == 1 ? pr1 : pr2);
            float qq = lane == 0 ? q0 : (lane == 1 ? q1 : q2);
            float bb = lane == 0 ? b20 : (lane == 1 ? b21 : b22);
            out_pos[s * 3 + lane] = pos_s[s * 3 + lane] + (pr + bb * qq) / cnt;
        }
    }
}

// ---------------- update GEMM: relu([x_d, aggr_x] @ W3 + b3) ----------------
__global__ __launch_bounds__(128) void out_kernel(
    const float* __restrict__ x, const float* __restrict__ W3,
    const float* __restrict__ b3, const int* __restrict__ idx_i,
    const float* __restrict__ aggr_x, float* __restrict__ out_x)
{
    __shared__ float rows[32][208];
    const int t = threadIdx.x;
    const int s0 = blockIdx.x * 32;
    const int sl = t >> 2, part = t & 3;
    const int s = s0 + sl;
    const int b = s >> 10;
    const int id = idx_i[s];
    {
        const float4* xr = (const float4*)(x + ((size_t)b * N_ + id) * D_);
        float4* rr = (float4*)&rows[sl][0];
#pragma unroll
        for (int q = 0; q < 4; ++q) rr[part * 4 + q] = xr[part * 4 + q];
        const float4* ar = (const float4*)(aggr_x + (size_t)s * H_);
        float4* rr2 = (float4*)&rows[sl][64];
#pragma unroll
        for (int q = 0; q < 8; ++q) rr2[part * 8 + q] = ar[part * 8 + q];
    }
    __syncthreads();
    float acc[32];
#pragma unroll
    for (int i = 0; i < 32; ++i) acc[i] = 0.f;
    for (int j4 = 0; j4 < 48; ++j4) {
        float w0 = W3[(j4 * 4 + 0) * H_ + t];
        float w1 = W3[(j4 * 4 + 1) * H_ + t];
        float w2 = W3[(j4 * 4 + 2) * H_ + t];
        float w3 = W3[(j4 * 4 + 3) * H_ + t];
#pragma unroll
        for (int i = 0; i < 32; ++i) {
            const float4 f = *(const float4*)&rows[i][j4 * 4];
            float a = acc[i];
            a = fmaf(f.x, w0, a); a = fmaf(f.y, w1, a);
            a = fmaf(f.z, w2, a); a = fmaf(f.w, w3, a);
            acc[i] = a;
        }
    }
    const float bb = b3[t];
#pragma unroll
    for (int i = 0; i < 32; ++i) {
        float v = acc[i] + bb;
        v = v > 0.f ? v : 0.f;
        out_x[(size_t)(s0 + i) * H_ + t] = v;
    }
}

extern "C" void kernel_launch(void* const* d_in, const int* in_sizes, int n_in,
                              void* d_out, int out_size, void* d_ws, size_t ws_size,
                              hipStream_t stream) {
    const float* x   = (const float*)d_in[0];
    const float* pos = (const float*)d_in[1];
    const float* W1  = (const float*)d_in[2];
    const float* b1  = (const float*)d_in[3];
    const float* W2  = (const float*)d_in[4];
    const float* b2  = (const float*)d_in[5];
    const float* W3  = (const float*)d_in[6];
    const float* b3  = (const float*)d_in[7];

    float* out_x   = (float*)d_out;                       // [16,1024,128]
    float* out_pos = (float*)d_out + 2097152;             // [16,1024,3]
    float* idx_f   = (float*)d_out + 2146304;             // [16,1024] as float

    char* ws = (char*)d_ws;
    int*      idx_i  = (int*)ws;                   // 16384 ints
    float*    pos_s  = (float*)(ws + 65536);       // 49152 floats
    int*      nbr    = (int*)(ws + 262144);        // 524288 ints
    float*    cntv   = (float*)(ws + 2359296);     // 16384 floats
    float*    aggr_x = (float*)(ws + 2424832);     // 2097152 floats
    ushort_t* x_bf16 = (ushort_t*)(ws + 10813440); // 16777216 ushorts (ends ~19.2MB)

    fps_kernel<<<B_, 256, 0, stream>>>(pos, idx_i, idx_f, pos_s);
    // nbr blocks 0..4095 + fused cvt blocks 4096..6143 (cvt hides in makespan)
    nbr_kernel<<<NBR_GRID_ + (B_ * N_ * D_) / (256 * 8), 256, 0, stream>>>(
        pos, pos_s, nbr, cntv, x, x_bf16);
    msg_kernel<<<(B_ * NS_) / 16, 256, 0, stream>>>(x_bf16, pos, W1, b1, W2, b2,
                                                    pos_s, nbr, cntv, aggr_x, out_pos);
    out_kernel<<<(B_ * NS_) / 32, 128, 0, stream>>>(x, W3, b3, idx_i, aggr_x, out_x);
}